// Round 13
// baseline (346.316 us; speedup 1.0000x reference)
//
#include <hip/hip_runtime.h>
#include <hip/hip_bf16.h>

typedef __attribute__((ext_vector_type(8))) short short8;
typedef __attribute__((ext_vector_type(4))) float f32x4;
typedef __attribute__((ext_vector_type(4))) unsigned short ushort4v;

#define MFMA_BF16(a, b, c) __builtin_amdgcn_mfma_f32_16x16x32_bf16((a), (b), (c), 0, 0, 0)
#define AS1 __attribute__((address_space(1)))
#define AS3 __attribute__((address_space(3)))

__device__ __forceinline__ unsigned short f2b(float f) {
  unsigned u = __float_as_uint(f);
  u += 0x7fffu + ((u >> 16) & 1u);
  return (unsigned short)(u >> 16);
}

// packed-K index: Kp[bh][l][d ^ ((l&7)<<3)]
__device__ __forceinline__ size_t kpack_idx(int row, int col) {
  int b = row >> 10, l = row & 1023, h = col >> 6, d = col & 63;
  return ((size_t)(b * 16 + h) << 16) + l * 64 + (d ^ ((l & 7) << 3));
}

// ---------------- fused cast f32 -> bf16, 8 segments ----------------
__global__ __launch_bounds__(256) void cast8(
    const float* s0, const float* s1, const float* s2, const float* s3,
    const float* s4, const float* s5, const float* s6, const float* s7,
    unsigned short* d0, unsigned short* d1, unsigned short* d2, unsigned short* d3,
    unsigned short* d4, unsigned short* d5, unsigned short* d6, unsigned short* d7,
    int n0, int n1, int n2, int n3, int n4, int n5, int n6, int n7) {
  const float* s; unsigned short* d; int n;
  switch (blockIdx.y) {
    case 0: s = s0; d = d0; n = n0; break;
    case 1: s = s1; d = d1; n = n1; break;
    case 2: s = s2; d = d2; n = n2; break;
    case 3: s = s3; d = d3; n = n3; break;
    case 4: s = s4; d = d4; n = n4; break;
    case 5: s = s5; d = d5; n = n5; break;
    case 6: s = s6; d = d6; n = n6; break;
    default: s = s7; d = d7; n = n7; break;
  }
  int stride = gridDim.x * blockDim.x;
  for (int i = blockIdx.x * blockDim.x + threadIdx.x; i < n; i += stride) {
    float4 v = reinterpret_cast<const float4*>(s)[i];
    ushort4v o;
    o.x = f2b(v.x); o.y = f2b(v.y); o.z = f2b(v.z); o.w = f2b(v.w);
    reinterpret_cast<ushort4v*>(d)[i] = o;
  }
}

// ------- GEMM: C = A @ W^T (+bias)(+resid)(relu), BK=64, XOR-swizzled ------
template <int RELU, int RES, int OUTF, int OUTB, int TM>
__global__ __launch_bounds__(256) void gemm_bt(
    const unsigned short* __restrict__ A, const unsigned short* __restrict__ W,
    const float* __restrict__ bias, const float* __restrict__ resid,
    float* __restrict__ outF, unsigned short* __restrict__ outB,
    int M, int N, int K) {
  constexpr int MI = TM / 32;
  __shared__ unsigned short lA[TM * 64];
  __shared__ unsigned short lB[128 * 64];
  int nbn = N >> 7;
  int nwg = gridDim.x;
  int id = blockIdx.x;
  { int q = nwg >> 3; id = (id & 7) * q + (id >> 3); }  // all grids %8 == 0
  int m0 = (id / nbn) * TM, n0 = (id % nbn) << 7;
  int lane = threadIdx.x & 63, wave = threadIdx.x >> 6;
  int wr = (wave >> 1) * (TM / 2), wc = (wave & 1) * 64;
  int rq = lane & 15, kq = (lane >> 4) * 8;
  int xr8 = (rq & 7) << 3;
  f32x4 acc[MI][4] = {};

  int t8 = threadIdx.x * 8;
  for (int kt = 0; kt < K; kt += 64) {
#pragma unroll
    for (int i = 0; i < MI; ++i) {  // A: TM*64 elems, MI rounds of 2048
      int e = t8 + i * 2048;
      int row = e >> 6;
      int gcol = (((e >> 3) & 7) ^ (row & 7)) << 3;
      __builtin_amdgcn_global_load_lds(
          (const AS1 void*)(A + (size_t)(m0 + row) * K + kt + gcol),
          (AS3 void*)(lA + e), 16, 0, 0);
    }
#pragma unroll
    for (int i = 0; i < 4; ++i) {  // B: 128*64 elems, 4 rounds
      int e = t8 + i * 2048;
      int row = e >> 6;
      int gcol = (((e >> 3) & 7) ^ (row & 7)) << 3;
      __builtin_amdgcn_global_load_lds(
          (const AS1 void*)(W + (size_t)(n0 + row) * K + kt + gcol),
          (AS3 void*)(lB + e), 16, 0, 0);
    }
    __syncthreads();
#pragma unroll
    for (int s = 0; s < 2; ++s) {
      short8 af[MI], bf[4];
#pragma unroll
      for (int i = 0; i < MI; ++i)
        af[i] = *reinterpret_cast<const short8*>(lA + (wr + i * 16 + rq) * 64 + ((s * 32 + kq) ^ xr8));
#pragma unroll
      for (int j = 0; j < 4; ++j)
        bf[j] = *reinterpret_cast<const short8*>(lB + (wc + j * 16 + rq) * 64 + ((s * 32 + kq) ^ xr8));
#pragma unroll
      for (int i = 0; i < MI; ++i)
#pragma unroll
        for (int j = 0; j < 4; ++j)
          acc[i][j] = MFMA_BF16(af[i], bf[j], acc[i][j]);
    }
    __syncthreads();
  }

  int r0 = (lane >> 4) * 4;
#pragma unroll
  for (int i = 0; i < MI; ++i) {
#pragma unroll
    for (int j = 0; j < 4; ++j) {
      int row = m0 + wr + i * 16 + r0;
      int col = n0 + wc + j * 16 + rq;
      float bv = bias[col];
#pragma unroll
      for (int r = 0; r < 4; ++r) {
        float v = acc[i][j][r] + bv;
        if (RES) v += resid[(size_t)(row + r) * N + col];
        if (RELU) v = fmaxf(v, 0.0f);
        if (OUTF) outF[(size_t)(row + r) * N + col] = v;
        if (OUTB) outB[(size_t)(row + r) * N + col] = f2b(v);
      }
    }
  }
}

// ------- fused QKV projections with A-reuse: grid 512, 2 blocks/CU ----------
// Blocks 0-255 (sel=0): one xb A-tile -> Q,K,V. Blocks 256-511: encb -> K,V.
// BK=32, 2-phase dbuf, 64-B rows chunk-swizzled (2-way = free).
__global__ __launch_bounds__(256, 2) void gemm_qkv_f(
    const unsigned short* __restrict__ xb, const unsigned short* __restrict__ encb,
    const unsigned short* __restrict__ wq, const unsigned short* __restrict__ wk,
    const unsigned short* __restrict__ wv,
    const float* __restrict__ bq, const float* __restrict__ bk, const float* __restrict__ bv,
    unsigned short* __restrict__ qb, unsigned short* __restrict__ kp1,
    unsigned short* __restrict__ vp1, unsigned short* __restrict__ kp2,
    unsigned short* __restrict__ vp2) {
  __shared__ unsigned short lA[2][4096];
  __shared__ unsigned short lB[2][3][4096];
  int id = blockIdx.x;             // 512
  id = (id & 7) * 64 + (id >> 3);  // bijective XCD swizzle (512 % 8 == 0)
  int sel = id >> 8;               // 0: x->QKV, 1: enc->KV
  int idx = id & 255;
  int m0 = (idx >> 3) << 7, col0 = (idx & 7) << 7;
  int nW = sel ? 2 : 3;
  const unsigned short* A = sel ? encb : xb;
  const unsigned short* W0 = sel ? wk : wq;
  const unsigned short* W1 = sel ? wv : wk;
  const unsigned short* W2 = wv;
  int lane = threadIdx.x & 63, wave = threadIdx.x >> 6;
  int wr = (wave >> 1) * 64, wc = (wave & 1) * 64;
  int rq = lane & 15, kq = (lane >> 4) * 8;
  int xk = ((rq >> 1) & 3) << 3;  // read-side chunk XOR
  f32x4 acc[3][4][4] = {};

  int e0 = threadIdx.x * 8;
#define STG(KT, BUF)                                                            \
  {                                                                             \
    _Pragma("unroll") for (int i = 0; i < 2; ++i) {                             \
      int e = e0 + i * 2048;                                                    \
      int row = e >> 5;                                                         \
      int gcol = ((((e >> 3) & 3) ^ ((row >> 1) & 3)) << 3);                    \
      __builtin_amdgcn_global_load_lds(                                         \
          (const AS1 void*)(A + (size_t)(m0 + row) * 1024 + (KT) + gcol),       \
          (AS3 void*)(&lA[BUF][e]), 16, 0, 0);                                  \
      __builtin_amdgcn_global_load_lds(                                         \
          (const AS1 void*)(W0 + (size_t)(col0 + row) * 1024 + (KT) + gcol),    \
          (AS3 void*)(&lB[BUF][0][e]), 16, 0, 0);                               \
      __builtin_amdgcn_global_load_lds(                                         \
          (const AS1 void*)(W1 + (size_t)(col0 + row) * 1024 + (KT) + gcol),    \
          (AS3 void*)(&lB[BUF][1][e]), 16, 0, 0);                               \
      if (!sel)                                                                 \
        __builtin_amdgcn_global_load_lds(                                       \
            (const AS1 void*)(W2 + (size_t)(col0 + row) * 1024 + (KT) + gcol),  \
            (AS3 void*)(&lB[BUF][2][e]), 16, 0, 0);                             \
    }                                                                           \
  }

  STG(0, 0);
  __syncthreads();
  for (int t = 0; t < 32; ++t) {
    int cur = t & 1;
    if (t + 1 < 32) STG((t + 1) << 5, cur ^ 1);
    short8 af[4];
#pragma unroll
    for (int i = 0; i < 4; ++i)
      af[i] = *reinterpret_cast<const short8*>(&lA[cur][(wr + i * 16 + rq) * 32 + (kq ^ xk)]);
#pragma unroll
    for (int w = 0; w < 3; ++w) {
      if (w < nW) {
        short8 bf[4];
#pragma unroll
        for (int j = 0; j < 4; ++j)
          bf[j] = *reinterpret_cast<const short8*>(&lB[cur][w][(wc + j * 16 + rq) * 32 + (kq ^ xk)]);
#pragma unroll
        for (int i = 0; i < 4; ++i)
#pragma unroll
          for (int j = 0; j < 4; ++j)
            acc[w][i][j] = MFMA_BF16(af[i], bf[j], acc[w][i][j]);
      }
    }
    __syncthreads();
  }
#undef STG

  int r0 = (lane >> 4) * 4;
#pragma unroll
  for (int w = 0; w < 3; ++w) {
    if (w >= nW) continue;
    const float* bias = sel ? (w == 0 ? bk : bv) : (w == 0 ? bq : (w == 1 ? bk : bv));
    unsigned short* outp = sel ? (w == 0 ? kp2 : vp2) : (w == 0 ? qb : (w == 1 ? kp1 : vp1));
    int pack = sel ? (w + 1) : w;
#pragma unroll
    for (int i = 0; i < 4; ++i) {
#pragma unroll
      for (int j = 0; j < 4; ++j) {
        int row0 = m0 + wr + i * 16 + r0;
        int col = col0 + wc + j * 16 + rq;
        float bv2 = bias[col];
        if (pack == 2) {
          int b = row0 >> 10, k0 = row0 & 1023, h = col >> 6, d = col & 63;
          size_t idx2 = ((size_t)((b * 16 + h) * 16 + (k0 >> 6)) << 12) + d * 64 + ((k0 & 63) ^ ((d & 7) << 3));
          ushort4v o;
          o.x = f2b(acc[w][i][j][0] + bv2);
          o.y = f2b(acc[w][i][j][1] + bv2);
          o.z = f2b(acc[w][i][j][2] + bv2);
          o.w = f2b(acc[w][i][j][3] + bv2);
          *reinterpret_cast<ushort4v*>(&outp[idx2]) = o;
        } else {
#pragma unroll
          for (int r = 0; r < 4; ++r) {
            int row = row0 + r;
            float v = acc[w][i][j][r] + bv2;
            if (pack == 0) outp[(size_t)row * 1024 + col] = f2b(v);
            else outp[kpack_idx(row, col)] = f2b(v);
          }
        }
      }
    }
  }
}

// ---------------- flash attention step (defer-max [T13], THR=4) ----------------
__device__ __forceinline__ void attn_step(
    const unsigned short* __restrict__ kcur, const unsigned short* __restrict__ vcur,
    unsigned short* __restrict__ plw, const short8* qf,
    f32x4* accd, float& m2, float& lsum,
    int rq, int hi, int kq, int xr, int wave, bool domask) {
  const float SC = 0.04508422f;  // (1/sqrt(1024)) * log2(e)
  f32x4 st[4];
  __builtin_amdgcn_s_setprio(1);
#pragma unroll
  for (int sub = 0; sub < 4; ++sub) {
    f32x4 z = {0.f, 0.f, 0.f, 0.f};
#pragma unroll
    for (int c = 0; c < 2; ++c) {
      short8 kf = *reinterpret_cast<const short8*>(
          &kcur[(sub * 16 + rq) * 64 + ((c * 32 + hi * 8) ^ xr)]);
      z = MFMA_BF16(kf, qf[c], z);
    }
    st[sub] = z * SC;
  }
  __builtin_amdgcn_s_setprio(0);
  if (domask) {
#pragma unroll
    for (int sub = 0; sub < 4; ++sub)
#pragma unroll
      for (int r = 0; r < 4; ++r)
        if (sub * 16 + hi * 4 + r > wave * 16 + rq) st[sub][r] = -1e9f;
  }
  f32x4 t0 = {fmaxf(st[0][0], st[1][0]), fmaxf(st[0][1], st[1][1]),
              fmaxf(st[0][2], st[1][2]), fmaxf(st[0][3], st[1][3])};
  f32x4 t1 = {fmaxf(st[2][0], st[3][0]), fmaxf(st[2][1], st[3][1]),
              fmaxf(st[2][2], st[3][2]), fmaxf(st[2][3], st[3][3])};
  float mx = fmaxf(fmaxf(fmaxf(t0[0], t1[0]), fmaxf(t0[1], t1[1])),
                   fmaxf(fmaxf(t0[2], t1[2]), fmaxf(t0[3], t1[3])));
  mx = fmaxf(mx, __shfl_xor(mx, 16, 64));
  mx = fmaxf(mx, __shfl_xor(mx, 32, 64));
  // defer-max: if no row grew past m2+4, keep old max (P bounded by 2^4)
  int skip = __all(mx <= m2 + 4.0f);
  float mn = m2, al = 1.0f;
  if (!skip) {
    mn = fmaxf(m2, mx);
    al = exp2f(m2 - mn);
    m2 = mn;
  }
  f32x4 e[4];
#pragma unroll
  for (int sub = 0; sub < 4; ++sub)
#pragma unroll
    for (int r = 0; r < 4; ++r) e[sub][r] = exp2f(st[sub][r] - mn);
  f32x4 s01 = e[0] + e[1], s23 = e[2] + e[3];
  f32x4 s = s01 + s23;
  float ps = (s[0] + s[1]) + (s[2] + s[3]);
  ps += __shfl_xor(ps, 16, 64);
  ps += __shfl_xor(ps, 32, 64);
#pragma unroll
  for (int sub = 0; sub < 4; ++sub) {
    unsigned w0 = (unsigned)f2b(e[sub][0]) | ((unsigned)f2b(e[sub][1]) << 16);
    unsigned w1 = (unsigned)f2b(e[sub][2]) | ((unsigned)f2b(e[sub][3]) << 16);
    uint2 w = make_uint2(w0, w1);
    *reinterpret_cast<uint2*>(&plw[rq * 64 + ((sub * 16 + hi * 4) ^ xr)]) = w;
  }
  if (skip) {
    lsum += ps;
  } else {
    lsum = lsum * al + ps;
    float alb[4];
#pragma unroll
    for (int r = 0; r < 4; ++r) alb[r] = __shfl(al, hi * 4 + r, 64);
#pragma unroll
    for (int d = 0; d < 4; ++d)
#pragma unroll
      for (int r = 0; r < 4; ++r) accd[d][r] *= alb[r];
  }
  short8 pf[2];
#pragma unroll
  for (int c = 0; c < 2; ++c)
    pf[c] = *reinterpret_cast<const short8*>(&plw[rq * 64 + ((c * 32 + hi * 8) ^ xr)]);
  __builtin_amdgcn_s_setprio(1);
#pragma unroll
  for (int d = 0; d < 4; ++d) {
#pragma unroll
    for (int c = 0; c < 2; ++c) {
      short8 vf = *reinterpret_cast<const short8*>(
          &vcur[(d * 16 + rq) * 64 + ((c * 32 + hi * 8) ^ xr)]);
      accd[d] = MFMA_BF16(pf[c], vf, accd[d]);
    }
  }
  __builtin_amdgcn_s_setprio(0);
}

// grid 1024: one q-tile per block -> 4 blocks/CU (16 waves/CU) for TLP.
// id: xcd = id&7; rest = id>>3; qtsel = rest&15 (varies fastest in dispatch
// order -> resident sets mix sizes); bh = xcd*8 + (rest>>4).
// causal: qt = 15-qtsel (heavy-first LPT). cross: qt = qtsel.
__global__ __launch_bounds__(256) void attn_kernel(
    const unsigned short* __restrict__ Q, const unsigned short* __restrict__ Kp,
    const unsigned short* __restrict__ Vp, unsigned short* __restrict__ O, int causal) {
  __shared__ unsigned short kls[2][4096];
  __shared__ unsigned short vls[2][4096];
  __shared__ unsigned short pls[4][1024];
  int id = blockIdx.x;
  int xcd = id & 7, rest = id >> 3;
  int qtsel = rest & 15, bhi = rest >> 4;
  int bh = xcd * 8 + bhi;
  int b = bh >> 4, h = bh & 15;
  int qt = causal ? (15 - qtsel) : qtsel;
  int lane = threadIdx.x & 63, wave = threadIdx.x >> 6;
  int rq = lane & 15, hi = lane >> 4, kq = hi * 8;
  int xr = (rq & 7) << 3;
  int sb = wave * 1024 + lane * 8;
  const unsigned short* Kbh = Kp + ((size_t)bh << 16);
  const unsigned short* Vbh = Vp + ((size_t)bh << 16);
  unsigned short* plw = pls[wave];

  int nkt = causal ? (qt + 1) : 16;
  int qrow0 = qt * 64 + wave * 16;
  short8 qf[2];
#pragma unroll
  for (int c = 0; c < 2; ++c)
    qf[c] = *reinterpret_cast<const short8*>(
        Q + (size_t)(b * 1024 + qrow0 + rq) * 1024 + h * 64 + c * 32 + kq);

  float m2 = -1e30f, lsum = 0.f;
  f32x4 accd[4] = {};

#pragma unroll
  for (int i = 0; i < 2; ++i) {
    __builtin_amdgcn_global_load_lds((const AS1 void*)(Kbh + sb + i * 512),
                                     (AS3 void*)(&kls[0][sb + i * 512]), 16, 0, 0);
    __builtin_amdgcn_global_load_lds((const AS1 void*)(Vbh + sb + i * 512),
                                     (AS3 void*)(&vls[0][sb + i * 512]), 16, 0, 0);
  }
  __syncthreads();

  int cur = 0;
  for (int kt = 0; kt < nkt; ++kt) {
    if (kt + 1 < nkt) {
      const unsigned short* kg = Kbh + (kt + 1) * 4096 + sb;
      const unsigned short* vg = Vbh + (kt + 1) * 4096 + sb;
#pragma unroll
      for (int i = 0; i < 2; ++i) {
        __builtin_amdgcn_global_load_lds((const AS1 void*)(kg + i * 512),
                                         (AS3 void*)(&kls[cur ^ 1][sb + i * 512]), 16, 0, 0);
        __builtin_amdgcn_global_load_lds((const AS1 void*)(vg + i * 512),
                                         (AS3 void*)(&vls[cur ^ 1][sb + i * 512]), 16, 0, 0);
      }
    }
    attn_step(kls[cur], vls[cur], plw, qf, accd, m2, lsum, rq, hi, kq, xr, wave,
              causal && kt == qt);
    __syncthreads();
    cur ^= 1;
  }

  float lb[4];
#pragma unroll
  for (int r = 0; r < 4; ++r) lb[r] = 1.0f / __shfl(lsum, hi * 4 + r, 64);
#pragma unroll
  for (int d = 0; d < 4; ++d)
#pragma unroll
    for (int r = 0; r < 4; ++r)
      O[(size_t)(b * 1024 + qrow0 + hi * 4 + r) * 1024 + h * 64 + d * 16 + rq] =
          f2b(accd[d][r] * lb[r]);
}

// ---------------- LayerNorm over 1024 ----------------
template <int OUTF, int OUTB>
__global__ __launch_bounds__(256) void ln_kernel(const float* __restrict__ X,
                                                 const float* __restrict__ g,
                                                 const float* __restrict__ be,
                                                 float* __restrict__ outF,
                                                 unsigned short* __restrict__ outB) {
  __shared__ float red[2][4];
  int row = blockIdx.x;
  int t = threadIdx.x;
  const float* xr = X + (size_t)row * 1024;
  float4 v = reinterpret_cast<const float4*>(xr)[t];
  float s = v.x + v.y + v.z + v.w;
  float ss = v.x * v.x + v.y * v.y + v.z * v.z + v.w * v.w;
#pragma unroll
  for (int off = 1; off < 64; off <<= 1) {
    s += __shfl_xor(s, off, 64);
    ss += __shfl_xor(ss, off, 64);
  }
  int wave = t >> 6;
  if ((t & 63) == 0) { red[0][wave] = s; red[1][wave] = ss; }
  __syncthreads();
  s = red[0][0] + red[0][1] + red[0][2] + red[0][3];
  ss = red[1][0] + red[1][1] + red[1][2] + red[1][3];
  float mu = s * (1.f / 1024.f);
  float var = ss * (1.f / 1024.f) - mu * mu;
  float rs = rsqrtf(var + 1e-5f);
  float4 gv = reinterpret_cast<const float4*>(g)[t];
  float4 bv = reinterpret_cast<const float4*>(be)[t];
  float o0 = (v.x - mu) * rs * gv.x + bv.x;
  float o1 = (v.y - mu) * rs * gv.y + bv.y;
  float o2 = (v.z - mu) * rs * gv.z + bv.z;
  float o3 = (v.w - mu) * rs * gv.w + bv.w;
  if (OUTF) {
    float4 o = make_float4(o0, o1, o2, o3);
    reinterpret_cast<float4*>(outF + (size_t)row * 1024)[t] = o;
  }
  if (OUTB) {
    ushort4v o;
    o.x = f2b(o0); o.y = f2b(o1); o.z = f2b(o2); o.w = f2b(o3);
    reinterpret_cast<ushort4v*>(outB + (size_t)row * 1024)[t] = o;
  }
}

extern "C" void kernel_launch(void* const* d_in, const int* in_sizes, int n_in,
                              void* d_out, int out_size, void* d_ws, size_t ws_size,
                              hipStream_t stream) {
  const float* x   = (const float*)d_in[0];
  const float* enc = (const float*)d_in[1];
  const float* wq = (const float*)d_in[4];  const float* bq = (const float*)d_in[5];
  const float* wk = (const float*)d_in[6];  const float* bk = (const float*)d_in[7];
  const float* wv = (const float*)d_in[8];  const float* bv = (const float*)d_in[9];
  const float* wo = (const float*)d_in[10]; const float* bo = (const float*)d_in[11];
  const float* w1 = (const float*)d_in[12]; const float* b1 = (const float*)d_in[13];
  const float* w2 = (const float*)d_in[14]; const float* b2 = (const float*)d_in[15];
  const float* g1 = (const float*)d_in[16]; const float* be1 = (const float*)d_in[17];
  const float* g2 = (const float*)d_in[18]; const float* be2 = (const float*)d_in[19];
  float* out = (float*)d_out;

  const int M = 4096;  // B*L
  char* ws = (char*)d_ws;
  size_t off = 0;
  auto alloc = [&](size_t bytes) -> char* {
    char* p = ws + off;
    off += (bytes + 255) & ~(size_t)255;
    return p;
  };
  unsigned short* xb   = (unsigned short*)alloc((size_t)M * 1024 * 2);
  unsigned short* encb = (unsigned short*)alloc((size_t)M * 1024 * 2);
  unsigned short* wqb  = (unsigned short*)alloc((size_t)1024 * 1024 * 2);
  unsigned short* wkb  = (unsigned short*)alloc((size_t)1024 * 1024 * 2);
  unsigned short* wvb  = (unsigned short*)alloc((size_t)1024 * 1024 * 2);
  unsigned short* wob  = (unsigned short*)alloc((size_t)1024 * 1024 * 2);
  unsigned short* w1b  = (unsigned short*)alloc((size_t)4096 * 1024 * 2);
  unsigned short* w2b  = (unsigned short*)alloc((size_t)4096 * 1024 * 2);
  unsigned short* qb   = (unsigned short*)alloc((size_t)M * 1024 * 2);
  unsigned short* kp1  = (unsigned short*)alloc((size_t)M * 1024 * 2);  // contiguous group:
  unsigned short* vp1  = (unsigned short*)alloc((size_t)M * 1024 * 2);  //   aliased by hb
  unsigned short* kp2  = (unsigned short*)alloc((size_t)M * 1024 * 2);
  unsigned short* vp2  = (unsigned short*)alloc((size_t)M * 1024 * 2);
  unsigned short* ab   = (unsigned short*)alloc((size_t)M * 1024 * 2);
  float* s1 = (float*)alloc((size_t)M * 1024 * 4);
  float* y1 = (float*)alloc((size_t)M * 1024 * 4);
  unsigned short* hb = kp1;  // 32MB: kp1..vp2 all dead after attn2
  unsigned short* y1b = xb;  // xb dead after gemm_qkv_f
  unsigned short* y2b = qb;  // qb dead after attn2
  float* y2 = y1;            // y1 dead after O2 projection

  dim3 b256(256);
  cast8<<<dim3(256, 8), b256, 0, stream>>>(
      x, enc, wq, wk, wv, wo, w1, w2,
      xb, encb, wqb, wkb, wvb, wob, w1b, w2b,
      M * 1024 / 4, M * 1024 / 4, 262144, 262144, 262144, 262144,
      4096 * 1024 / 4, 4096 * 1024 / 4);

  // ---- all input-dependent projections in one launch (A-reuse fused) ----
  gemm_qkv_f<<<512, b256, 0, stream>>>(xb, encb, wqb, wkb, wvb, bq, bk, bv,
                                       qb, kp1, vp1, kp2, vp2);

  // ---- self attention ----
  attn_kernel<<<1024, b256, 0, stream>>>(qb, kp1, vp1, ab, 1);
  gemm_bt<0, 1, 1, 0, 64><<<512, b256, 0, stream>>>(ab, wob, bo, x, s1, nullptr, M, 1024, 1024);
  ln_kernel<1, 1><<<4096, b256, 0, stream>>>(s1, g1, be1, y1, y1b);

  // ---- cross attention ----
  gemm_bt<0, 0, 0, 1, 64><<<512, b256, 0, stream>>>(y1b, wqb, bq, nullptr, nullptr, qb, M, 1024, 1024);
  attn_kernel<<<1024, b256, 0, stream>>>(qb, kp2, vp2, ab, 0);
  gemm_bt<0, 1, 1, 0, 64><<<512, b256, 0, stream>>>(ab, wob, bo, y1, s1, nullptr, M, 1024, 1024);
  ln_kernel<1, 1><<<4096, b256, 0, stream>>>(s1, g1, be1, y2, y2b);

  // ---- FFN ----
  gemm_bt<1, 0, 0, 1, 128><<<1024, b256, 0, stream>>>(y2b, w1b, b1, nullptr, nullptr, hb, M, 4096, 1024);
  gemm_bt<0, 1, 1, 0, 64><<<512, b256, 0, stream>>>(hb, w2b, b2, y2, s1, nullptr, M, 1024, 4096);
  ln_kernel<1, 0><<<4096, b256, 0, stream>>>(s1, g2, be2, out, nullptr);

  (void)in_sizes; (void)n_in; (void)out_size; (void)ws_size;
}

// Round 14
// 337.785 us; speedup vs baseline: 1.0253x; 1.0253x over previous
//
#include <hip/hip_runtime.h>
#include <hip/hip_bf16.h>

typedef __attribute__((ext_vector_type(8))) short short8;
typedef __attribute__((ext_vector_type(4))) float f32x4;
typedef __attribute__((ext_vector_type(4))) unsigned short ushort4v;

#define MFMA_BF16(a, b, c) __builtin_amdgcn_mfma_f32_16x16x32_bf16((a), (b), (c), 0, 0, 0)
#define AS1 __attribute__((address_space(1)))
#define AS3 __attribute__((address_space(3)))

__device__ __forceinline__ unsigned short f2b(float f) {
  unsigned u = __float_as_uint(f);
  u += 0x7fffu + ((u >> 16) & 1u);
  return (unsigned short)(u >> 16);
}

// packed-K index: Kp[bh][l][d ^ ((l&7)<<3)]
__device__ __forceinline__ size_t kpack_idx(int row, int col) {
  int b = row >> 10, l = row & 1023, h = col >> 6, d = col & 63;
  return ((size_t)(b * 16 + h) << 16) + l * 64 + (d ^ ((l & 7) << 3));
}

// ---------------- fused cast f32 -> bf16, 8 segments ----------------
__global__ __launch_bounds__(256) void cast8(
    const float* s0, const float* s1, const float* s2, const float* s3,
    const float* s4, const float* s5, const float* s6, const float* s7,
    unsigned short* d0, unsigned short* d1, unsigned short* d2, unsigned short* d3,
    unsigned short* d4, unsigned short* d5, unsigned short* d6, unsigned short* d7,
    int n0, int n1, int n2, int n3, int n4, int n5, int n6, int n7) {
  const float* s; unsigned short* d; int n;
  switch (blockIdx.y) {
    case 0: s = s0; d = d0; n = n0; break;
    case 1: s = s1; d = d1; n = n1; break;
    case 2: s = s2; d = d2; n = n2; break;
    case 3: s = s3; d = d3; n = n3; break;
    case 4: s = s4; d = d4; n = n4; break;
    case 5: s = s5; d = d5; n = n5; break;
    case 6: s = s6; d = d6; n = n6; break;
    default: s = s7; d = d7; n = n7; break;
  }
  int stride = gridDim.x * blockDim.x;
  for (int i = blockIdx.x * blockDim.x + threadIdx.x; i < n; i += stride) {
    float4 v = reinterpret_cast<const float4*>(s)[i];
    ushort4v o;
    o.x = f2b(v.x); o.y = f2b(v.y); o.z = f2b(v.z); o.w = f2b(v.w);
    reinterpret_cast<ushort4v*>(d)[i] = o;
  }
}

// ------- GEMM: C = A @ W^T (+bias)(+resid)(relu), BK=64, XOR-swizzled ------
// SPLITK=2: grid doubles; half h covers K-range [h*K/2,(h+1)*K/2) writing raw
// f32 partials to outF + h*M*N (bias added by half 0 only; no resid/relu).
template <int RELU, int RES, int OUTF, int OUTB, int TM, int SPLITK>
__global__ __launch_bounds__(256) void gemm_bt(
    const unsigned short* __restrict__ A, const unsigned short* __restrict__ W,
    const float* __restrict__ bias, const float* __restrict__ resid,
    float* __restrict__ outF, unsigned short* __restrict__ outB,
    int M, int N, int K) {
  constexpr int MI = TM / 32;
  __shared__ unsigned short lA[TM * 64];
  __shared__ unsigned short lB[128 * 64];
  int nbn = N >> 7;
  int nwg = gridDim.x;
  int id = blockIdx.x;
  { int q = nwg >> 3; id = (id & 7) * q + (id >> 3); }  // all grids %8 == 0
  int half = 0;
  if (SPLITK == 2) { half = id & 1; id >>= 1; }
  int m0 = (id / nbn) * TM, n0 = (id % nbn) << 7;
  int lane = threadIdx.x & 63, wave = threadIdx.x >> 6;
  int wr = (wave >> 1) * (TM / 2), wc = (wave & 1) * 64;
  int rq = lane & 15, kq = (lane >> 4) * 8;
  int xr8 = (rq & 7) << 3;
  f32x4 acc[MI][4] = {};

  int kBeg = (SPLITK == 2) ? half * (K >> 1) : 0;
  int kEnd = (SPLITK == 2) ? kBeg + (K >> 1) : K;
  int t8 = threadIdx.x * 8;
  for (int kt = kBeg; kt < kEnd; kt += 64) {
#pragma unroll
    for (int i = 0; i < MI; ++i) {  // A: TM*64 elems, MI rounds of 2048
      int e = t8 + i * 2048;
      int row = e >> 6;
      int gcol = (((e >> 3) & 7) ^ (row & 7)) << 3;
      __builtin_amdgcn_global_load_lds(
          (const AS1 void*)(A + (size_t)(m0 + row) * K + kt + gcol),
          (AS3 void*)(lA + e), 16, 0, 0);
    }
#pragma unroll
    for (int i = 0; i < 4; ++i) {  // B: 128*64 elems, 4 rounds
      int e = t8 + i * 2048;
      int row = e >> 6;
      int gcol = (((e >> 3) & 7) ^ (row & 7)) << 3;
      __builtin_amdgcn_global_load_lds(
          (const AS1 void*)(W + (size_t)(n0 + row) * K + kt + gcol),
          (AS3 void*)(lB + e), 16, 0, 0);
    }
    __syncthreads();
#pragma unroll
    for (int s = 0; s < 2; ++s) {
      short8 af[MI], bf[4];
#pragma unroll
      for (int i = 0; i < MI; ++i)
        af[i] = *reinterpret_cast<const short8*>(lA + (wr + i * 16 + rq) * 64 + ((s * 32 + kq) ^ xr8));
#pragma unroll
      for (int j = 0; j < 4; ++j)
        bf[j] = *reinterpret_cast<const short8*>(lB + (wc + j * 16 + rq) * 64 + ((s * 32 + kq) ^ xr8));
#pragma unroll
      for (int i = 0; i < MI; ++i)
#pragma unroll
        for (int j = 0; j < 4; ++j)
          acc[i][j] = MFMA_BF16(af[i], bf[j], acc[i][j]);
    }
    __syncthreads();
  }

  float* outFp = (SPLITK == 2) ? outF + (size_t)half * M * N : outF;
  int r0 = (lane >> 4) * 4;
#pragma unroll
  for (int i = 0; i < MI; ++i) {
#pragma unroll
    for (int j = 0; j < 4; ++j) {
      int row = m0 + wr + i * 16 + r0;
      int col = n0 + wc + j * 16 + rq;
      float bv = (SPLITK == 2 && half) ? 0.0f : bias[col];
#pragma unroll
      for (int r = 0; r < 4; ++r) {
        float v = acc[i][j][r] + bv;
        if (RES) v += resid[(size_t)(row + r) * N + col];
        if (RELU) v = fmaxf(v, 0.0f);
        if (OUTF) outFp[(size_t)(row + r) * N + col] = v;
        if (OUTB) outB[(size_t)(row + r) * N + col] = f2b(v);
      }
    }
  }
}

// ------- fused QKV projections with A-reuse: grid 512, 2 blocks/CU ----------
__global__ __launch_bounds__(256, 2) void gemm_qkv_f(
    const unsigned short* __restrict__ xb, const unsigned short* __restrict__ encb,
    const unsigned short* __restrict__ wq, const unsigned short* __restrict__ wk,
    const unsigned short* __restrict__ wv,
    const float* __restrict__ bq, const float* __restrict__ bk, const float* __restrict__ bv,
    unsigned short* __restrict__ qb, unsigned short* __restrict__ kp1,
    unsigned short* __restrict__ vp1, unsigned short* __restrict__ kp2,
    unsigned short* __restrict__ vp2) {
  __shared__ unsigned short lA[2][4096];
  __shared__ unsigned short lB[2][3][4096];
  int id = blockIdx.x;             // 512
  id = (id & 7) * 64 + (id >> 3);  // bijective XCD swizzle
  int sel = id >> 8;               // 0: x->QKV, 1: enc->KV
  int idx = id & 255;
  int m0 = (idx >> 3) << 7, col0 = (idx & 7) << 7;
  int nW = sel ? 2 : 3;
  const unsigned short* A = sel ? encb : xb;
  const unsigned short* W0 = sel ? wk : wq;
  const unsigned short* W1 = sel ? wv : wk;
  const unsigned short* W2 = wv;
  int lane = threadIdx.x & 63, wave = threadIdx.x >> 6;
  int wr = (wave >> 1) * 64, wc = (wave & 1) * 64;
  int rq = lane & 15, kq = (lane >> 4) * 8;
  int xk = ((rq >> 1) & 3) << 3;  // read-side chunk XOR
  f32x4 acc[3][4][4] = {};

  int e0 = threadIdx.x * 8;
#define STG(KT, BUF)                                                            \
  {                                                                             \
    _Pragma("unroll") for (int i = 0; i < 2; ++i) {                             \
      int e = e0 + i * 2048;                                                    \
      int row = e >> 5;                                                         \
      int gcol = ((((e >> 3) & 3) ^ ((row >> 1) & 3)) << 3);                    \
      __builtin_amdgcn_global_load_lds(                                         \
          (const AS1 void*)(A + (size_t)(m0 + row) * 1024 + (KT) + gcol),       \
          (AS3 void*)(&lA[BUF][e]), 16, 0, 0);                                  \
      __builtin_amdgcn_global_load_lds(                                         \
          (const AS1 void*)(W0 + (size_t)(col0 + row) * 1024 + (KT) + gcol),    \
          (AS3 void*)(&lB[BUF][0][e]), 16, 0, 0);                               \
      __builtin_amdgcn_global_load_lds(                                         \
          (const AS1 void*)(W1 + (size_t)(col0 + row) * 1024 + (KT) + gcol),    \
          (AS3 void*)(&lB[BUF][1][e]), 16, 0, 0);                               \
      if (!sel)                                                                 \
        __builtin_amdgcn_global_load_lds(                                       \
            (const AS1 void*)(W2 + (size_t)(col0 + row) * 1024 + (KT) + gcol),  \
            (AS3 void*)(&lB[BUF][2][e]), 16, 0, 0);                             \
    }                                                                           \
  }

  STG(0, 0);
  __syncthreads();
  for (int t = 0; t < 32; ++t) {
    int cur = t & 1;
    if (t + 1 < 32) STG((t + 1) << 5, cur ^ 1);
    short8 af[4];
#pragma unroll
    for (int i = 0; i < 4; ++i)
      af[i] = *reinterpret_cast<const short8*>(&lA[cur][(wr + i * 16 + rq) * 32 + (kq ^ xk)]);
#pragma unroll
    for (int w = 0; w < 3; ++w) {
      if (w < nW) {
        short8 bf[4];
#pragma unroll
        for (int j = 0; j < 4; ++j)
          bf[j] = *reinterpret_cast<const short8*>(&lB[cur][w][(wc + j * 16 + rq) * 32 + (kq ^ xk)]);
#pragma unroll
        for (int i = 0; i < 4; ++i)
#pragma unroll
          for (int j = 0; j < 4; ++j)
            acc[w][i][j] = MFMA_BF16(af[i], bf[j], acc[w][i][j]);
      }
    }
    __syncthreads();
  }
#undef STG

  int r0 = (lane >> 4) * 4;
#pragma unroll
  for (int w = 0; w < 3; ++w) {
    if (w >= nW) continue;
    const float* bias = sel ? (w == 0 ? bk : bv) : (w == 0 ? bq : (w == 1 ? bk : bv));
    unsigned short* outp = sel ? (w == 0 ? kp2 : vp2) : (w == 0 ? qb : (w == 1 ? kp1 : vp1));
    int pack = sel ? (w + 1) : w;
#pragma unroll
    for (int i = 0; i < 4; ++i) {
#pragma unroll
      for (int j = 0; j < 4; ++j) {
        int row0 = m0 + wr + i * 16 + r0;
        int col = col0 + wc + j * 16 + rq;
        float bv2 = bias[col];
        if (pack == 2) {
          int b = row0 >> 10, k0 = row0 & 1023, h = col >> 6, d = col & 63;
          size_t idx2 = ((size_t)((b * 16 + h) * 16 + (k0 >> 6)) << 12) + d * 64 + ((k0 & 63) ^ ((d & 7) << 3));
          ushort4v o;
          o.x = f2b(acc[w][i][j][0] + bv2);
          o.y = f2b(acc[w][i][j][1] + bv2);
          o.z = f2b(acc[w][i][j][2] + bv2);
          o.w = f2b(acc[w][i][j][3] + bv2);
          *reinterpret_cast<ushort4v*>(&outp[idx2]) = o;
        } else {
#pragma unroll
          for (int r = 0; r < 4; ++r) {
            int row = row0 + r;
            float v = acc[w][i][j][r] + bv2;
            if (pack == 0) outp[(size_t)row * 1024 + col] = f2b(v);
            else outp[kpack_idx(row, col)] = f2b(v);
          }
        }
      }
    }
  }
}

// ---------------- flash attention step (defer-max [T13], THR=4) ----------------
__device__ __forceinline__ void attn_step(
    const unsigned short* __restrict__ kcur, const unsigned short* __restrict__ vcur,
    unsigned short* __restrict__ plw, const short8* qf,
    f32x4* accd, float& m2, float& lsum,
    int rq, int hi, int kq, int xr, int wave, bool domask) {
  const float SC = 0.04508422f;  // (1/sqrt(1024)) * log2(e)
  f32x4 st[4];
  __builtin_amdgcn_s_setprio(1);
#pragma unroll
  for (int sub = 0; sub < 4; ++sub) {
    f32x4 z = {0.f, 0.f, 0.f, 0.f};
#pragma unroll
    for (int c = 0; c < 2; ++c) {
      short8 kf = *reinterpret_cast<const short8*>(
          &kcur[(sub * 16 + rq) * 64 + ((c * 32 + hi * 8) ^ xr)]);
      z = MFMA_BF16(kf, qf[c], z);
    }
    st[sub] = z * SC;
  }
  __builtin_amdgcn_s_setprio(0);
  if (domask) {
#pragma unroll
    for (int sub = 0; sub < 4; ++sub)
#pragma unroll
      for (int r = 0; r < 4; ++r)
        if (sub * 16 + hi * 4 + r > wave * 16 + rq) st[sub][r] = -1e9f;
  }
  f32x4 t0 = {fmaxf(st[0][0], st[1][0]), fmaxf(st[0][1], st[1][1]),
              fmaxf(st[0][2], st[1][2]), fmaxf(st[0][3], st[1][3])};
  f32x4 t1 = {fmaxf(st[2][0], st[3][0]), fmaxf(st[2][1], st[3][1]),
              fmaxf(st[2][2], st[3][2]), fmaxf(st[2][3], st[3][3])};
  float mx = fmaxf(fmaxf(fmaxf(t0[0], t1[0]), fmaxf(t0[1], t1[1])),
                   fmaxf(fmaxf(t0[2], t1[2]), fmaxf(t0[3], t1[3])));
  mx = fmaxf(mx, __shfl_xor(mx, 16, 64));
  mx = fmaxf(mx, __shfl_xor(mx, 32, 64));
  int skip = __all(mx <= m2 + 4.0f);
  float mn = m2, al = 1.0f;
  if (!skip) {
    mn = fmaxf(m2, mx);
    al = exp2f(m2 - mn);
    m2 = mn;
  }
  f32x4 e[4];
#pragma unroll
  for (int sub = 0; sub < 4; ++sub)
#pragma unroll
    for (int r = 0; r < 4; ++r) e[sub][r] = exp2f(st[sub][r] - mn);
  f32x4 s01 = e[0] + e[1], s23 = e[2] + e[3];
  f32x4 s = s01 + s23;
  float ps = (s[0] + s[1]) + (s[2] + s[3]);
  ps += __shfl_xor(ps, 16, 64);
  ps += __shfl_xor(ps, 32, 64);
#pragma unroll
  for (int sub = 0; sub < 4; ++sub) {
    unsigned w0 = (unsigned)f2b(e[sub][0]) | ((unsigned)f2b(e[sub][1]) << 16);
    unsigned w1 = (unsigned)f2b(e[sub][2]) | ((unsigned)f2b(e[sub][3]) << 16);
    uint2 w = make_uint2(w0, w1);
    *reinterpret_cast<uint2*>(&plw[rq * 64 + ((sub * 16 + hi * 4) ^ xr)]) = w;
  }
  if (skip) {
    lsum += ps;
  } else {
    lsum = lsum * al + ps;
    float alb[4];
#pragma unroll
    for (int r = 0; r < 4; ++r) alb[r] = __shfl(al, hi * 4 + r, 64);
#pragma unroll
    for (int d = 0; d < 4; ++d)
#pragma unroll
      for (int r = 0; r < 4; ++r) accd[d][r] *= alb[r];
  }
  short8 pf[2];
#pragma unroll
  for (int c = 0; c < 2; ++c)
    pf[c] = *reinterpret_cast<const short8*>(&plw[rq * 64 + ((c * 32 + hi * 8) ^ xr)]);
  __builtin_amdgcn_s_setprio(1);
#pragma unroll
  for (int d = 0; d < 4; ++d) {
#pragma unroll
    for (int c = 0; c < 2; ++c) {
      short8 vf = *reinterpret_cast<const short8*>(
          &vcur[(d * 16 + rq) * 64 + ((c * 32 + hi * 8) ^ xr)]);
      accd[d] = MFMA_BF16(pf[c], vf, accd[d]);
    }
  }
  __builtin_amdgcn_s_setprio(0);
}

// grid 1024: one q-tile per block -> 4 blocks/CU for TLP.
__global__ __launch_bounds__(256) void attn_kernel(
    const unsigned short* __restrict__ Q, const unsigned short* __restrict__ Kp,
    const unsigned short* __restrict__ Vp, unsigned short* __restrict__ O, int causal) {
  __shared__ unsigned short kls[2][4096];
  __shared__ unsigned short vls[2][4096];
  __shared__ unsigned short pls[4][1024];
  int id = blockIdx.x;
  int xcd = id & 7, rest = id >> 3;
  int qtsel = rest & 15, bhi = rest >> 4;
  int bh = xcd * 8 + bhi;
  int b = bh >> 4, h = bh & 15;
  int qt = causal ? (15 - qtsel) : qtsel;
  int lane = threadIdx.x & 63, wave = threadIdx.x >> 6;
  int rq = lane & 15, hi = lane >> 4, kq = hi * 8;
  int xr = (rq & 7) << 3;
  int sb = wave * 1024 + lane * 8;
  const unsigned short* Kbh = Kp + ((size_t)bh << 16);
  const unsigned short* Vbh = Vp + ((size_t)bh << 16);
  unsigned short* plw = pls[wave];

  int nkt = causal ? (qt + 1) : 16;
  int qrow0 = qt * 64 + wave * 16;
  short8 qf[2];
#pragma unroll
  for (int c = 0; c < 2; ++c)
    qf[c] = *reinterpret_cast<const short8*>(
        Q + (size_t)(b * 1024 + qrow0 + rq) * 1024 + h * 64 + c * 32 + kq);

  float m2 = -1e30f, lsum = 0.f;
  f32x4 accd[4] = {};

#pragma unroll
  for (int i = 0; i < 2; ++i) {
    __builtin_amdgcn_global_load_lds((const AS1 void*)(Kbh + sb + i * 512),
                                     (AS3 void*)(&kls[0][sb + i * 512]), 16, 0, 0);
    __builtin_amdgcn_global_load_lds((const AS1 void*)(Vbh + sb + i * 512),
                                     (AS3 void*)(&vls[0][sb + i * 512]), 16, 0, 0);
  }
  __syncthreads();

  int cur = 0;
  for (int kt = 0; kt < nkt; ++kt) {
    if (kt + 1 < nkt) {
      const unsigned short* kg = Kbh + (kt + 1) * 4096 + sb;
      const unsigned short* vg = Vbh + (kt + 1) * 4096 + sb;
#pragma unroll
      for (int i = 0; i < 2; ++i) {
        __builtin_amdgcn_global_load_lds((const AS1 void*)(kg + i * 512),
                                         (AS3 void*)(&kls[cur ^ 1][sb + i * 512]), 16, 0, 0);
        __builtin_amdgcn_global_load_lds((const AS1 void*)(vg + i * 512),
                                         (AS3 void*)(&vls[cur ^ 1][sb + i * 512]), 16, 0, 0);
      }
    }
    attn_step(kls[cur], vls[cur], plw, qf, accd, m2, lsum, rq, hi, kq, xr, wave,
              causal && kt == qt);
    __syncthreads();
    cur ^= 1;
  }

  float lb[4];
#pragma unroll
  for (int r = 0; r < 4; ++r) lb[r] = 1.0f / __shfl(lsum, hi * 4 + r, 64);
#pragma unroll
  for (int d = 0; d < 4; ++d)
#pragma unroll
    for (int r = 0; r < 4; ++r)
      O[(size_t)(b * 1024 + qrow0 + hi * 4 + r) * 1024 + h * 64 + d * 16 + rq] =
          f2b(accd[d][r] * lb[r]);
}

// ---------------- LayerNorm over 1024 ----------------
template <int OUTF, int OUTB>
__global__ __launch_bounds__(256) void ln_kernel(const float* __restrict__ X,
                                                 const float* __restrict__ g,
                                                 const float* __restrict__ be,
                                                 float* __restrict__ outF,
                                                 unsigned short* __restrict__ outB) {
  __shared__ float red[2][4];
  int row = blockIdx.x;
  int t = threadIdx.x;
  const float* xr = X + (size_t)row * 1024;
  float4 v = reinterpret_cast<const float4*>(xr)[t];
  float s = v.x + v.y + v.z + v.w;
  float ss = v.x * v.x + v.y * v.y + v.z * v.z + v.w * v.w;
#pragma unroll
  for (int off = 1; off < 64; off <<= 1) {
    s += __shfl_xor(s, off, 64);
    ss += __shfl_xor(ss, off, 64);
  }
  int wave = t >> 6;
  if ((t & 63) == 0) { red[0][wave] = s; red[1][wave] = ss; }
  __syncthreads();
  s = red[0][0] + red[0][1] + red[0][2] + red[0][3];
  ss = red[1][0] + red[1][1] + red[1][2] + red[1][3];
  float mu = s * (1.f / 1024.f);
  float var = ss * (1.f / 1024.f) - mu * mu;
  float rs = rsqrtf(var + 1e-5f);
  float4 gv = reinterpret_cast<const float4*>(g)[t];
  float4 bv = reinterpret_cast<const float4*>(be)[t];
  float o0 = (v.x - mu) * rs * gv.x + bv.x;
  float o1 = (v.y - mu) * rs * gv.y + bv.y;
  float o2 = (v.z - mu) * rs * gv.z + bv.z;
  float o3 = (v.w - mu) * rs * gv.w + bv.w;
  if (OUTF) {
    float4 o = make_float4(o0, o1, o2, o3);
    reinterpret_cast<float4*>(outF + (size_t)row * 1024)[t] = o;
  }
  if (OUTB) {
    ushort4v o;
    o.x = f2b(o0); o.y = f2b(o1); o.z = f2b(o2); o.w = f2b(o3);
    reinterpret_cast<ushort4v*>(outB + (size_t)row * 1024)[t] = o;
  }
}

// ---- final LayerNorm over (a + b + resid): consumes split-K partials ----
__global__ __launch_bounds__(256) void ln2_kernel(const float* __restrict__ Xa,
                                                  const float* __restrict__ Xb,
                                                  const float* __restrict__ R,
                                                  const float* __restrict__ g,
                                                  const float* __restrict__ be,
                                                  float* __restrict__ outF) {
  __shared__ float red[2][4];
  int row = blockIdx.x;
  int t = threadIdx.x;
  float4 va = reinterpret_cast<const float4*>(Xa + (size_t)row * 1024)[t];
  float4 vb = reinterpret_cast<const float4*>(Xb + (size_t)row * 1024)[t];
  float4 vr = reinterpret_cast<const float4*>(R + (size_t)row * 1024)[t];
  float4 v = make_float4(va.x + vb.x + vr.x, va.y + vb.y + vr.y,
                         va.z + vb.z + vr.z, va.w + vb.w + vr.w);
  float s = v.x + v.y + v.z + v.w;
  float ss = v.x * v.x + v.y * v.y + v.z * v.z + v.w * v.w;
#pragma unroll
  for (int off = 1; off < 64; off <<= 1) {
    s += __shfl_xor(s, off, 64);
    ss += __shfl_xor(ss, off, 64);
  }
  int wave = t >> 6;
  if ((t & 63) == 0) { red[0][wave] = s; red[1][wave] = ss; }
  __syncthreads();
  s = red[0][0] + red[0][1] + red[0][2] + red[0][3];
  ss = red[1][0] + red[1][1] + red[1][2] + red[1][3];
  float mu = s * (1.f / 1024.f);
  float var = ss * (1.f / 1024.f) - mu * mu;
  float rs = rsqrtf(var + 1e-5f);
  float4 gv = reinterpret_cast<const float4*>(g)[t];
  float4 bv = reinterpret_cast<const float4*>(be)[t];
  float4 o = make_float4((v.x - mu) * rs * gv.x + bv.x, (v.y - mu) * rs * gv.y + bv.y,
                         (v.z - mu) * rs * gv.z + bv.z, (v.w - mu) * rs * gv.w + bv.w);
  reinterpret_cast<float4*>(outF + (size_t)row * 1024)[t] = o;
}

extern "C" void kernel_launch(void* const* d_in, const int* in_sizes, int n_in,
                              void* d_out, int out_size, void* d_ws, size_t ws_size,
                              hipStream_t stream) {
  const float* x   = (const float*)d_in[0];
  const float* enc = (const float*)d_in[1];
  const float* wq = (const float*)d_in[4];  const float* bq = (const float*)d_in[5];
  const float* wk = (const float*)d_in[6];  const float* bk = (const float*)d_in[7];
  const float* wv = (const float*)d_in[8];  const float* bv = (const float*)d_in[9];
  const float* wo = (const float*)d_in[10]; const float* bo = (const float*)d_in[11];
  const float* w1 = (const float*)d_in[12]; const float* b1 = (const float*)d_in[13];
  const float* w2 = (const float*)d_in[14]; const float* b2 = (const float*)d_in[15];
  const float* g1 = (const float*)d_in[16]; const float* be1 = (const float*)d_in[17];
  const float* g2 = (const float*)d_in[18]; const float* be2 = (const float*)d_in[19];
  float* out = (float*)d_out;

  const int M = 4096;  // B*L
  char* ws = (char*)d_ws;
  size_t off = 0;
  auto alloc = [&](size_t bytes) -> char* {
    char* p = ws + off;
    off += (bytes + 255) & ~(size_t)255;
    return p;
  };
  unsigned short* xb   = (unsigned short*)alloc((size_t)M * 1024 * 2);
  unsigned short* encb = (unsigned short*)alloc((size_t)M * 1024 * 2);
  unsigned short* wqb  = (unsigned short*)alloc((size_t)1024 * 1024 * 2);
  unsigned short* wkb  = (unsigned short*)alloc((size_t)1024 * 1024 * 2);
  unsigned short* wvb  = (unsigned short*)alloc((size_t)1024 * 1024 * 2);
  unsigned short* wob  = (unsigned short*)alloc((size_t)1024 * 1024 * 2);
  unsigned short* w1b  = (unsigned short*)alloc((size_t)4096 * 1024 * 2);
  unsigned short* w2b  = (unsigned short*)alloc((size_t)4096 * 1024 * 2);
  unsigned short* qb   = (unsigned short*)alloc((size_t)M * 1024 * 2);
  unsigned short* kp1  = (unsigned short*)alloc((size_t)M * 1024 * 2);  // contiguous group:
  unsigned short* vp1  = (unsigned short*)alloc((size_t)M * 1024 * 2);  //   aliased by hb
  unsigned short* kp2  = (unsigned short*)alloc((size_t)M * 1024 * 2);
  unsigned short* vp2  = (unsigned short*)alloc((size_t)M * 1024 * 2);
  unsigned short* ab   = (unsigned short*)alloc((size_t)M * 1024 * 2);
  float* s1 = (float*)alloc((size_t)2 * M * 1024 * 4);  // 2 halves for split-K
  float* y1 = (float*)alloc((size_t)M * 1024 * 4);
  unsigned short* hb = kp1;  // 32MB: kp1..vp2 all dead after attn2
  unsigned short* y1b = xb;  // xb dead after gemm_qkv_f
  unsigned short* y2b = qb;  // qb dead after attn2
  float* y2 = y1;            // y1 dead after O2 projection

  dim3 b256(256);
  cast8<<<dim3(256, 8), b256, 0, stream>>>(
      x, enc, wq, wk, wv, wo, w1, w2,
      xb, encb, wqb, wkb, wvb, wob, w1b, w2b,
      M * 1024 / 4, M * 1024 / 4, 262144, 262144, 262144, 262144,
      4096 * 1024 / 4, 4096 * 1024 / 4);

  // ---- all input-dependent projections in one launch (A-reuse fused) ----
  gemm_qkv_f<<<512, b256, 0, stream>>>(xb, encb, wqb, wkb, wvb, bq, bk, bv,
                                       qb, kp1, vp1, kp2, vp2);

  // ---- self attention ----
  attn_kernel<<<1024, b256, 0, stream>>>(qb, kp1, vp1, ab, 1);
  gemm_bt<0, 1, 1, 0, 64, 1><<<512, b256, 0, stream>>>(ab, wob, bo, x, s1, nullptr, M, 1024, 1024);
  ln_kernel<1, 1><<<4096, b256, 0, stream>>>(s1, g1, be1, y1, y1b);

  // ---- cross attention ----
  gemm_bt<0, 0, 0, 1, 64, 1><<<512, b256, 0, stream>>>(y1b, wqb, bq, nullptr, nullptr, qb, M, 1024, 1024);
  attn_kernel<<<1024, b256, 0, stream>>>(qb, kp2, vp2, ab, 0);
  gemm_bt<0, 1, 1, 0, 64, 1><<<512, b256, 0, stream>>>(ab, wob, bo, y1, s1, nullptr, M, 1024, 1024);
  ln_kernel<1, 1><<<4096, b256, 0, stream>>>(s1, g1, be1, y2, y2b);

  // ---- FFN ----
  gemm_bt<1, 0, 0, 1, 128, 1><<<1024, b256, 0, stream>>>(y2b, w1b, b1, nullptr, nullptr, hb, M, 4096, 1024);
  // FFN2: TM=128 tile at 2 blocks/CU via split-K=2 (grid 512; f32 partials).
  gemm_bt<0, 0, 1, 0, 128, 2><<<512, b256, 0, stream>>>(hb, w2b, b2, nullptr, s1, nullptr, M, 1024, 4096);
  ln2_kernel<<<4096, b256, 0, stream>>>(s1, s1 + (size_t)M * 1024, y2, g2, be2, out);

  (void)in_sizes; (void)n_in; (void)out_size; (void)ws_size;
}

// Round 15
// 332.684 us; speedup vs baseline: 1.0410x; 1.0153x over previous
//
#include <hip/hip_runtime.h>
#include <hip/hip_bf16.h>

typedef __attribute__((ext_vector_type(8))) short short8;
typedef __attribute__((ext_vector_type(4))) float f32x4;
typedef __attribute__((ext_vector_type(4))) unsigned short ushort4v;

#define MFMA_BF16(a, b, c) __builtin_amdgcn_mfma_f32_16x16x32_bf16((a), (b), (c), 0, 0, 0)
#define AS1 __attribute__((address_space(1)))
#define AS3 __attribute__((address_space(3)))

__device__ __forceinline__ unsigned short f2b(float f) {
  unsigned u = __float_as_uint(f);
  u += 0x7fffu + ((u >> 16) & 1u);
  return (unsigned short)(u >> 16);
}

// packed-K index: Kp[bh][l][d ^ ((l&7)<<3)]
__device__ __forceinline__ size_t kpack_idx(int row, int col) {
  int b = row >> 10, l = row & 1023, h = col >> 6, d = col & 63;
  return ((size_t)(b * 16 + h) << 16) + l * 64 + (d ^ ((l & 7) << 3));
}

// ---------------- fused cast f32 -> bf16, 8 segments ----------------
__global__ __launch_bounds__(256) void cast8(
    const float* s0, const float* s1, const float* s2, const float* s3,
    const float* s4, const float* s5, const float* s6, const float* s7,
    unsigned short* d0, unsigned short* d1, unsigned short* d2, unsigned short* d3,
    unsigned short* d4, unsigned short* d5, unsigned short* d6, unsigned short* d7,
    int n0, int n1, int n2, int n3, int n4, int n5, int n6, int n7) {
  const float* s; unsigned short* d; int n;
  switch (blockIdx.y) {
    case 0: s = s0; d = d0; n = n0; break;
    case 1: s = s1; d = d1; n = n1; break;
    case 2: s = s2; d = d2; n = n2; break;
    case 3: s = s3; d = d3; n = n3; break;
    case 4: s = s4; d = d4; n = n4; break;
    case 5: s = s5; d = d5; n = n5; break;
    case 6: s = s6; d = d6; n = n6; break;
    default: s = s7; d = d7; n = n7; break;
  }
  int stride = gridDim.x * blockDim.x;
  for (int i = blockIdx.x * blockDim.x + threadIdx.x; i < n; i += stride) {
    float4 v = reinterpret_cast<const float4*>(s)[i];
    ushort4v o;
    o.x = f2b(v.x); o.y = f2b(v.y); o.z = f2b(v.z); o.w = f2b(v.w);
    reinterpret_cast<ushort4v*>(d)[i] = o;
  }
}

// ------- GEMM: C = A @ W^T (+bias)(+resid)(relu), BK=64, XOR-swizzled ------
// SPLITK=2: grid doubles; half h covers K-range [h*K/2,(h+1)*K/2) writing raw
// f32 partials to outF + h*M*N (bias added by half 0 only; no resid/relu).
template <int RELU, int RES, int OUTF, int OUTB, int TM, int SPLITK>
__global__ __launch_bounds__(256) void gemm_bt(
    const unsigned short* __restrict__ A, const unsigned short* __restrict__ W,
    const float* __restrict__ bias, const float* __restrict__ resid,
    float* __restrict__ outF, unsigned short* __restrict__ outB,
    int M, int N, int K) {
  constexpr int MI = TM / 32;
  __shared__ unsigned short lA[TM * 64];
  __shared__ unsigned short lB[128 * 64];
  int nbn = N >> 7;
  int nwg = gridDim.x;
  int id = blockIdx.x;
  { int q = nwg >> 3; id = (id & 7) * q + (id >> 3); }  // all grids %8 == 0
  int half = 0;
  if (SPLITK == 2) { half = id & 1; id >>= 1; }
  int m0 = (id / nbn) * TM, n0 = (id % nbn) << 7;
  int lane = threadIdx.x & 63, wave = threadIdx.x >> 6;
  int wr = (wave >> 1) * (TM / 2), wc = (wave & 1) * 64;
  int rq = lane & 15, kq = (lane >> 4) * 8;
  int xr8 = (rq & 7) << 3;
  f32x4 acc[MI][4] = {};

  int kBeg = (SPLITK == 2) ? half * (K >> 1) : 0;
  int kEnd = (SPLITK == 2) ? kBeg + (K >> 1) : K;
  int t8 = threadIdx.x * 8;
  for (int kt = kBeg; kt < kEnd; kt += 64) {
#pragma unroll
    for (int i = 0; i < MI; ++i) {  // A: TM*64 elems, MI rounds of 2048
      int e = t8 + i * 2048;
      int row = e >> 6;
      int gcol = (((e >> 3) & 7) ^ (row & 7)) << 3;
      __builtin_amdgcn_global_load_lds(
          (const AS1 void*)(A + (size_t)(m0 + row) * K + kt + gcol),
          (AS3 void*)(lA + e), 16, 0, 0);
    }
#pragma unroll
    for (int i = 0; i < 4; ++i) {  // B: 128*64 elems, 4 rounds
      int e = t8 + i * 2048;
      int row = e >> 6;
      int gcol = (((e >> 3) & 7) ^ (row & 7)) << 3;
      __builtin_amdgcn_global_load_lds(
          (const AS1 void*)(W + (size_t)(n0 + row) * K + kt + gcol),
          (AS3 void*)(lB + e), 16, 0, 0);
    }
    __syncthreads();
#pragma unroll
    for (int s = 0; s < 2; ++s) {
      short8 af[MI], bf[4];
#pragma unroll
      for (int i = 0; i < MI; ++i)
        af[i] = *reinterpret_cast<const short8*>(lA + (wr + i * 16 + rq) * 64 + ((s * 32 + kq) ^ xr8));
#pragma unroll
      for (int j = 0; j < 4; ++j)
        bf[j] = *reinterpret_cast<const short8*>(lB + (wc + j * 16 + rq) * 64 + ((s * 32 + kq) ^ xr8));
#pragma unroll
      for (int i = 0; i < MI; ++i)
#pragma unroll
        for (int j = 0; j < 4; ++j)
          acc[i][j] = MFMA_BF16(af[i], bf[j], acc[i][j]);
    }
    __syncthreads();
  }

  float* outFp = (SPLITK == 2) ? outF + (size_t)half * M * N : outF;
  int r0 = (lane >> 4) * 4;
#pragma unroll
  for (int i = 0; i < MI; ++i) {
#pragma unroll
    for (int j = 0; j < 4; ++j) {
      int row = m0 + wr + i * 16 + r0;
      int col = n0 + wc + j * 16 + rq;
      float bv = (SPLITK == 2 && half) ? 0.0f : bias[col];
#pragma unroll
      for (int r = 0; r < 4; ++r) {
        float v = acc[i][j][r] + bv;
        if (RES) v += resid[(size_t)(row + r) * N + col];
        if (RELU) v = fmaxf(v, 0.0f);
        if (OUTF) outFp[(size_t)(row + r) * N + col] = v;
        if (OUTB) outB[(size_t)(row + r) * N + col] = f2b(v);
      }
    }
  }
}

// ------- fused QKV projections with A-reuse: grid 512, 2 blocks/CU ----------
// Dispatch-round balance: blocks 0-255 = sel0 (x->QKV, 48 MFMA/iter), blocks
// 256-511 = sel1 (enc->KV, 32 MFMA/iter). Each CU gets one of each round ->
// one heavy + one light block (uniform 80 MFMA-units/CU, no same-sel tail).
__global__ __launch_bounds__(256, 2) void gemm_qkv_f(
    const unsigned short* __restrict__ xb, const unsigned short* __restrict__ encb,
    const unsigned short* __restrict__ wq, const unsigned short* __restrict__ wk,
    const unsigned short* __restrict__ wv,
    const float* __restrict__ bq, const float* __restrict__ bk, const float* __restrict__ bv,
    unsigned short* __restrict__ qb, unsigned short* __restrict__ kp1,
    unsigned short* __restrict__ vp1, unsigned short* __restrict__ kp2,
    unsigned short* __restrict__ vp2) {
  __shared__ unsigned short lA[2][4096];
  __shared__ unsigned short lB[2][3][4096];
  int orig = blockIdx.x;           // 512
  int sel = orig >> 8;             // round 0: sel0, round 1: sel1
  int inner = orig & 255;
  inner = (inner & 7) * 32 + (inner >> 3);  // XCD swizzle within round (256%8==0)
  int m0 = (inner >> 3) << 7, col0 = (inner & 7) << 7;
  int nW = sel ? 2 : 3;
  const unsigned short* A = sel ? encb : xb;
  const unsigned short* W0 = sel ? wk : wq;
  const unsigned short* W1 = sel ? wv : wk;
  const unsigned short* W2 = wv;
  int lane = threadIdx.x & 63, wave = threadIdx.x >> 6;
  int wr = (wave >> 1) * 64, wc = (wave & 1) * 64;
  int rq = lane & 15, kq = (lane >> 4) * 8;
  int xk = ((rq >> 1) & 3) << 3;  // read-side chunk XOR
  f32x4 acc[3][4][4] = {};

  int e0 = threadIdx.x * 8;
#define STG(KT, BUF)                                                            \
  {                                                                             \
    _Pragma("unroll") for (int i = 0; i < 2; ++i) {                             \
      int e = e0 + i * 2048;                                                    \
      int row = e >> 5;                                                         \
      int gcol = ((((e >> 3) & 3) ^ ((row >> 1) & 3)) << 3);                    \
      __builtin_amdgcn_global_load_lds(                                         \
          (const AS1 void*)(A + (size_t)(m0 + row) * 1024 + (KT) + gcol),       \
          (AS3 void*)(&lA[BUF][e]), 16, 0, 0);                                  \
      __builtin_amdgcn_global_load_lds(                                         \
          (const AS1 void*)(W0 + (size_t)(col0 + row) * 1024 + (KT) + gcol),    \
          (AS3 void*)(&lB[BUF][0][e]), 16, 0, 0);                               \
      __builtin_amdgcn_global_load_lds(                                         \
          (const AS1 void*)(W1 + (size_t)(col0 + row) * 1024 + (KT) + gcol),    \
          (AS3 void*)(&lB[BUF][1][e]), 16, 0, 0);                               \
      if (!sel)                                                                 \
        __builtin_amdgcn_global_load_lds(                                       \
            (const AS1 void*)(W2 + (size_t)(col0 + row) * 1024 + (KT) + gcol),  \
            (AS3 void*)(&lB[BUF][2][e]), 16, 0, 0);                             \
    }                                                                           \
  }

  STG(0, 0);
  __syncthreads();
  for (int t = 0; t < 32; ++t) {
    int cur = t & 1;
    if (t + 1 < 32) STG((t + 1) << 5, cur ^ 1);
    short8 af[4];
#pragma unroll
    for (int i = 0; i < 4; ++i)
      af[i] = *reinterpret_cast<const short8*>(&lA[cur][(wr + i * 16 + rq) * 32 + (kq ^ xk)]);
#pragma unroll
    for (int w = 0; w < 3; ++w) {
      if (w < nW) {
        short8 bf[4];
#pragma unroll
        for (int j = 0; j < 4; ++j)
          bf[j] = *reinterpret_cast<const short8*>(&lB[cur][w][(wc + j * 16 + rq) * 32 + (kq ^ xk)]);
#pragma unroll
        for (int i = 0; i < 4; ++i)
#pragma unroll
          for (int j = 0; j < 4; ++j)
            acc[w][i][j] = MFMA_BF16(af[i], bf[j], acc[w][i][j]);
      }
    }
    __syncthreads();
  }
#undef STG

  int r0 = (lane >> 4) * 4;
#pragma unroll
  for (int w = 0; w < 3; ++w) {
    if (w >= nW) continue;
    const float* bias = sel ? (w == 0 ? bk : bv) : (w == 0 ? bq : (w == 1 ? bk : bv));
    unsigned short* outp = sel ? (w == 0 ? kp2 : vp2) : (w == 0 ? qb : (w == 1 ? kp1 : vp1));
    int pack = sel ? (w + 1) : w;
#pragma unroll
    for (int i = 0; i < 4; ++i) {
#pragma unroll
      for (int j = 0; j < 4; ++j) {
        int row0 = m0 + wr + i * 16 + r0;
        int col = col0 + wc + j * 16 + rq;
        float bv2 = bias[col];
        if (pack == 2) {
          int b = row0 >> 10, k0 = row0 & 1023, h = col >> 6, d = col & 63;
          size_t idx2 = ((size_t)((b * 16 + h) * 16 + (k0 >> 6)) << 12) + d * 64 + ((k0 & 63) ^ ((d & 7) << 3));
          ushort4v o;
          o.x = f2b(acc[w][i][j][0] + bv2);
          o.y = f2b(acc[w][i][j][1] + bv2);
          o.z = f2b(acc[w][i][j][2] + bv2);
          o.w = f2b(acc[w][i][j][3] + bv2);
          *reinterpret_cast<ushort4v*>(&outp[idx2]) = o;
        } else {
#pragma unroll
          for (int r = 0; r < 4; ++r) {
            int row = row0 + r;
            float v = acc[w][i][j][r] + bv2;
            if (pack == 0) outp[(size_t)row * 1024 + col] = f2b(v);
            else outp[kpack_idx(row, col)] = f2b(v);
          }
        }
      }
    }
  }
}

// ---------------- flash attention step (defer-max [T13], THR=4) ----------------
__device__ __forceinline__ void attn_step(
    const unsigned short* __restrict__ kcur, const unsigned short* __restrict__ vcur,
    unsigned short* __restrict__ plw, const short8* qf,
    f32x4* accd, float& m2, float& lsum,
    int rq, int hi, int kq, int xr, int wave, bool domask) {
  const float SC = 0.04508422f;  // (1/sqrt(1024)) * log2(e)
  f32x4 st[4];
  __builtin_amdgcn_s_setprio(1);
#pragma unroll
  for (int sub = 0; sub < 4; ++sub) {
    f32x4 z = {0.f, 0.f, 0.f, 0.f};
#pragma unroll
    for (int c = 0; c < 2; ++c) {
      short8 kf = *reinterpret_cast<const short8*>(
          &kcur[(sub * 16 + rq) * 64 + ((c * 32 + hi * 8) ^ xr)]);
      z = MFMA_BF16(kf, qf[c], z);
    }
    st[sub] = z * SC;
  }
  __builtin_amdgcn_s_setprio(0);
  if (domask) {
#pragma unroll
    for (int sub = 0; sub < 4; ++sub)
#pragma unroll
      for (int r = 0; r < 4; ++r)
        if (sub * 16 + hi * 4 + r > wave * 16 + rq) st[sub][r] = -1e9f;
  }
  f32x4 t0 = {fmaxf(st[0][0], st[1][0]), fmaxf(st[0][1], st[1][1]),
              fmaxf(st[0][2], st[1][2]), fmaxf(st[0][3], st[1][3])};
  f32x4 t1 = {fmaxf(st[2][0], st[3][0]), fmaxf(st[2][1], st[3][1]),
              fmaxf(st[2][2], st[3][2]), fmaxf(st[2][3], st[3][3])};
  float mx = fmaxf(fmaxf(fmaxf(t0[0], t1[0]), fmaxf(t0[1], t1[1])),
                   fmaxf(fmaxf(t0[2], t1[2]), fmaxf(t0[3], t1[3])));
  mx = fmaxf(mx, __shfl_xor(mx, 16, 64));
  mx = fmaxf(mx, __shfl_xor(mx, 32, 64));
  int skip = __all(mx <= m2 + 4.0f);
  float mn = m2, al = 1.0f;
  if (!skip) {
    mn = fmaxf(m2, mx);
    al = exp2f(m2 - mn);
    m2 = mn;
  }
  f32x4 e[4];
#pragma unroll
  for (int sub = 0; sub < 4; ++sub)
#pragma unroll
    for (int r = 0; r < 4; ++r) e[sub][r] = exp2f(st[sub][r] - mn);
  f32x4 s01 = e[0] + e[1], s23 = e[2] + e[3];
  f32x4 s = s01 + s23;
  float ps = (s[0] + s[1]) + (s[2] + s[3]);
  ps += __shfl_xor(ps, 16, 64);
  ps += __shfl_xor(ps, 32, 64);
#pragma unroll
  for (int sub = 0; sub < 4; ++sub) {
    unsigned w0 = (unsigned)f2b(e[sub][0]) | ((unsigned)f2b(e[sub][1]) << 16);
    unsigned w1 = (unsigned)f2b(e[sub][2]) | ((unsigned)f2b(e[sub][3]) << 16);
    uint2 w = make_uint2(w0, w1);
    *reinterpret_cast<uint2*>(&plw[rq * 64 + ((sub * 16 + hi * 4) ^ xr)]) = w;
  }
  if (skip) {
    lsum += ps;
  } else {
    lsum = lsum * al + ps;
    float alb[4];
#pragma unroll
    for (int r = 0; r < 4; ++r) alb[r] = __shfl(al, hi * 4 + r, 64);
#pragma unroll
    for (int d = 0; d < 4; ++d)
#pragma unroll
      for (int r = 0; r < 4; ++r) accd[d][r] *= alb[r];
  }
  short8 pf[2];
#pragma unroll
  for (int c = 0; c < 2; ++c)
    pf[c] = *reinterpret_cast<const short8*>(&plw[rq * 64 + ((c * 32 + hi * 8) ^ xr)]);
  __builtin_amdgcn_s_setprio(1);
#pragma unroll
  for (int d = 0; d < 4; ++d) {
#pragma unroll
    for (int c = 0; c < 2; ++c) {
      short8 vf = *reinterpret_cast<const short8*>(
          &vcur[(d * 16 + rq) * 64 + ((c * 32 + hi * 8) ^ xr)]);
      accd[d] = MFMA_BF16(pf[c], vf, accd[d]);
    }
  }
  __builtin_amdgcn_s_setprio(0);
}

// grid 1024: one q-tile per block -> 4 blocks/CU for TLP.
__global__ __launch_bounds__(256) void attn_kernel(
    const unsigned short* __restrict__ Q, const unsigned short* __restrict__ Kp,
    const unsigned short* __restrict__ Vp, unsigned short* __restrict__ O, int causal) {
  __shared__ unsigned short kls[2][4096];
  __shared__ unsigned short vls[2][4096];
  __shared__ unsigned short pls[4][1024];
  int id = blockIdx.x;
  int xcd = id & 7, rest = id >> 3;
  int qtsel = rest & 15, bhi = rest >> 4;
  int bh = xcd * 8 + bhi;
  int b = bh >> 4, h = bh & 15;
  int qt = causal ? (15 - qtsel) : qtsel;
  int lane = threadIdx.x & 63, wave = threadIdx.x >> 6;
  int rq = lane & 15, hi = lane >> 4, kq = hi * 8;
  int xr = (rq & 7) << 3;
  int sb = wave * 1024 + lane * 8;
  const unsigned short* Kbh = Kp + ((size_t)bh << 16);
  const unsigned short* Vbh = Vp + ((size_t)bh << 16);
  unsigned short* plw = pls[wave];

  int nkt = causal ? (qt + 1) : 16;
  int qrow0 = qt * 64 + wave * 16;
  short8 qf[2];
#pragma unroll
  for (int c = 0; c < 2; ++c)
    qf[c] = *reinterpret_cast<const short8*>(
        Q + (size_t)(b * 1024 + qrow0 + rq) * 1024 + h * 64 + c * 32 + kq);

  float m2 = -1e30f, lsum = 0.f;
  f32x4 accd[4] = {};

#pragma unroll
  for (int i = 0; i < 2; ++i) {
    __builtin_amdgcn_global_load_lds((const AS1 void*)(Kbh + sb + i * 512),
                                     (AS3 void*)(&kls[0][sb + i * 512]), 16, 0, 0);
    __builtin_amdgcn_global_load_lds((const AS1 void*)(Vbh + sb + i * 512),
                                     (AS3 void*)(&vls[0][sb + i * 512]), 16, 0, 0);
  }
  __syncthreads();

  int cur = 0;
  for (int kt = 0; kt < nkt; ++kt) {
    if (kt + 1 < nkt) {
      const unsigned short* kg = Kbh + (kt + 1) * 4096 + sb;
      const unsigned short* vg = Vbh + (kt + 1) * 4096 + sb;
#pragma unroll
      for (int i = 0; i < 2; ++i) {
        __builtin_amdgcn_global_load_lds((const AS1 void*)(kg + i * 512),
                                         (AS3 void*)(&kls[cur ^ 1][sb + i * 512]), 16, 0, 0);
        __builtin_amdgcn_global_load_lds((const AS1 void*)(vg + i * 512),
                                         (AS3 void*)(&vls[cur ^ 1][sb + i * 512]), 16, 0, 0);
      }
    }
    attn_step(kls[cur], vls[cur], plw, qf, accd, m2, lsum, rq, hi, kq, xr, wave,
              causal && kt == qt);
    __syncthreads();
    cur ^= 1;
  }

  float lb[4];
#pragma unroll
  for (int r = 0; r < 4; ++r) lb[r] = 1.0f / __shfl(lsum, hi * 4 + r, 64);
#pragma unroll
  for (int d = 0; d < 4; ++d)
#pragma unroll
    for (int r = 0; r < 4; ++r)
      O[(size_t)(b * 1024 + qrow0 + hi * 4 + r) * 1024 + h * 64 + d * 16 + rq] =
          f2b(accd[d][r] * lb[r]);
}

// ---------------- LayerNorm over 1024 ----------------
template <int OUTF, int OUTB>
__global__ __launch_bounds__(256) void ln_kernel(const float* __restrict__ X,
                                                 const float* __restrict__ g,
                                                 const float* __restrict__ be,
                                                 float* __restrict__ outF,
                                                 unsigned short* __restrict__ outB) {
  __shared__ float red[2][4];
  int row = blockIdx.x;
  int t = threadIdx.x;
  const float* xr = X + (size_t)row * 1024;
  float4 v = reinterpret_cast<const float4*>(xr)[t];
  float s = v.x + v.y + v.z + v.w;
  float ss = v.x * v.x + v.y * v.y + v.z * v.z + v.w * v.w;
#pragma unroll
  for (int off = 1; off < 64; off <<= 1) {
    s += __shfl_xor(s, off, 64);
    ss += __shfl_xor(ss, off, 64);
  }
  int wave = t >> 6;
  if ((t & 63) == 0) { red[0][wave] = s; red[1][wave] = ss; }
  __syncthreads();
  s = red[0][0] + red[0][1] + red[0][2] + red[0][3];
  ss = red[1][0] + red[1][1] + red[1][2] + red[1][3];
  float mu = s * (1.f / 1024.f);
  float var = ss * (1.f / 1024.f) - mu * mu;
  float rs = rsqrtf(var + 1e-5f);
  float4 gv = reinterpret_cast<const float4*>(g)[t];
  float4 bv = reinterpret_cast<const float4*>(be)[t];
  float o0 = (v.x - mu) * rs * gv.x + bv.x;
  float o1 = (v.y - mu) * rs * gv.y + bv.y;
  float o2 = (v.z - mu) * rs * gv.z + bv.z;
  float o3 = (v.w - mu) * rs * gv.w + bv.w;
  if (OUTF) {
    float4 o = make_float4(o0, o1, o2, o3);
    reinterpret_cast<float4*>(outF + (size_t)row * 1024)[t] = o;
  }
  if (OUTB) {
    ushort4v o;
    o.x = f2b(o0); o.y = f2b(o1); o.z = f2b(o2); o.w = f2b(o3);
    reinterpret_cast<ushort4v*>(outB + (size_t)row * 1024)[t] = o;
  }
}

// ---- final LayerNorm over (a + b + resid): consumes split-K partials ----
__global__ __launch_bounds__(256) void ln2_kernel(const float* __restrict__ Xa,
                                                  const float* __restrict__ Xb,
                                                  const float* __restrict__ R,
                                                  const float* __restrict__ g,
                                                  const float* __restrict__ be,
                                                  float* __restrict__ outF) {
  __shared__ float red[2][4];
  int row = blockIdx.x;
  int t = threadIdx.x;
  float4 va = reinterpret_cast<const float4*>(Xa + (size_t)row * 1024)[t];
  float4 vb = reinterpret_cast<const float4*>(Xb + (size_t)row * 1024)[t];
  float4 vr = reinterpret_cast<const float4*>(R + (size_t)row * 1024)[t];
  float4 v = make_float4(va.x + vb.x + vr.x, va.y + vb.y + vr.y,
                         va.z + vb.z + vr.z, va.w + vb.w + vr.w);
  float s = v.x + v.y + v.z + v.w;
  float ss = v.x * v.x + v.y * v.y + v.z * v.z + v.w * v.w;
#pragma unroll
  for (int off = 1; off < 64; off <<= 1) {
    s += __shfl_xor(s, off, 64);
    ss += __shfl_xor(ss, off, 64);
  }
  int wave = t >> 6;
  if ((t & 63) == 0) { red[0][wave] = s; red[1][wave] = ss; }
  __syncthreads();
  s = red[0][0] + red[0][1] + red[0][2] + red[0][3];
  ss = red[1][0] + red[1][1] + red[1][2] + red[1][3];
  float mu = s * (1.f / 1024.f);
  float var = ss * (1.f / 1024.f) - mu * mu;
  float rs = rsqrtf(var + 1e-5f);
  float4 gv = reinterpret_cast<const float4*>(g)[t];
  float4 bv = reinterpret_cast<const float4*>(be)[t];
  float4 o = make_float4((v.x - mu) * rs * gv.x + bv.x, (v.y - mu) * rs * gv.y + bv.y,
                         (v.z - mu) * rs * gv.z + bv.z, (v.w - mu) * rs * gv.w + bv.w);
  reinterpret_cast<float4*>(outF + (size_t)row * 1024)[t] = o;
}

extern "C" void kernel_launch(void* const* d_in, const int* in_sizes, int n_in,
                              void* d_out, int out_size, void* d_ws, size_t ws_size,
                              hipStream_t stream) {
  const float* x   = (const float*)d_in[0];
  const float* enc = (const float*)d_in[1];
  const float* wq = (const float*)d_in[4];  const float* bq = (const float*)d_in[5];
  const float* wk = (const float*)d_in[6];  const float* bk = (const float*)d_in[7];
  const float* wv = (const float*)d_in[8];  const float* bv = (const float*)d_in[9];
  const float* wo = (const float*)d_in[10]; const float* bo = (const float*)d_in[11];
  const float* w1 = (const float*)d_in[12]; const float* b1 = (const float*)d_in[13];
  const float* w2 = (const float*)d_in[14]; const float* b2 = (const float*)d_in[15];
  const float* g1 = (const float*)d_in[16]; const float* be1 = (const float*)d_in[17];
  const float* g2 = (const float*)d_in[18]; const float* be2 = (const float*)d_in[19];
  float* out = (float*)d_out;

  const int M = 4096;  // B*L
  char* ws = (char*)d_ws;
  size_t off = 0;
  auto alloc = [&](size_t bytes) -> char* {
    char* p = ws + off;
    off += (bytes + 255) & ~(size_t)255;
    return p;
  };
  unsigned short* xb   = (unsigned short*)alloc((size_t)M * 1024 * 2);
  unsigned short* encb = (unsigned short*)alloc((size_t)M * 1024 * 2);
  unsigned short* wqb  = (unsigned short*)alloc((size_t)1024 * 1024 * 2);
  unsigned short* wkb  = (unsigned short*)alloc((size_t)1024 * 1024 * 2);
  unsigned short* wvb  = (unsigned short*)alloc((size_t)1024 * 1024 * 2);
  unsigned short* wob  = (unsigned short*)alloc((size_t)1024 * 1024 * 2);
  unsigned short* w1b  = (unsigned short*)alloc((size_t)4096 * 1024 * 2);
  unsigned short* w2b  = (unsigned short*)alloc((size_t)4096 * 1024 * 2);
  unsigned short* qb   = (unsigned short*)alloc((size_t)M * 1024 * 2);
  unsigned short* kp1  = (unsigned short*)alloc((size_t)M * 1024 * 2);  // contiguous group:
  unsigned short* vp1  = (unsigned short*)alloc((size_t)M * 1024 * 2);  //   aliased by hb
  unsigned short* kp2  = (unsigned short*)alloc((size_t)M * 1024 * 2);
  unsigned short* vp2  = (unsigned short*)alloc((size_t)M * 1024 * 2);
  unsigned short* ab   = (unsigned short*)alloc((size_t)M * 1024 * 2);
  float* s1 = (float*)alloc((size_t)2 * M * 1024 * 4);  // 2 halves for split-K
  float* y1 = (float*)alloc((size_t)M * 1024 * 4);
  unsigned short* hb = kp1;  // 32MB: kp1..vp2 all dead after attn2
  unsigned short* y1b = xb;  // xb dead after gemm_qkv_f
  unsigned short* y2b = qb;  // qb dead after attn2
  float* y2 = y1;            // y1 dead after O2 projection

  dim3 b256(256);
  cast8<<<dim3(256, 8), b256, 0, stream>>>(
      x, enc, wq, wk, wv, wo, w1, w2,
      xb, encb, wqb, wkb, wvb, wob, w1b, w2b,
      M * 1024 / 4, M * 1024 / 4, 262144, 262144, 262144, 262144,
      4096 * 1024 / 4, 4096 * 1024 / 4);

  // ---- all input-dependent projections in one launch (A-reuse fused) ----
  gemm_qkv_f<<<512, b256, 0, stream>>>(xb, encb, wqb, wkb, wvb, bq, bk, bv,
                                       qb, kp1, vp1, kp2, vp2);

  // ---- self attention ----
  attn_kernel<<<1024, b256, 0, stream>>>(qb, kp1, vp1, ab, 1);
  gemm_bt<0, 1, 1, 0, 64, 1><<<512, b256, 0, stream>>>(ab, wob, bo, x, s1, nullptr, M, 1024, 1024);
  ln_kernel<1, 1><<<4096, b256, 0, stream>>>(s1, g1, be1, y1, y1b);

  // ---- cross attention ----
  gemm_bt<0, 0, 0, 1, 64, 1><<<512, b256, 0, stream>>>(y1b, wqb, bq, nullptr, nullptr, qb, M, 1024, 1024);
  attn_kernel<<<1024, b256, 0, stream>>>(qb, kp2, vp2, ab, 0);
  gemm_bt<0, 1, 1, 0, 64, 1><<<512, b256, 0, stream>>>(ab, wob, bo, y1, s1, nullptr, M, 1024, 1024);
  ln_kernel<1, 1><<<4096, b256, 0, stream>>>(s1, g1, be1, y2, y2b);

  // ---- FFN ----
  gemm_bt<1, 0, 0, 1, 128, 1><<<1024, b256, 0, stream>>>(y2b, w1b, b1, nullptr, nullptr, hb, M, 4096, 1024);
  // FFN2: TM=128 tile at 2 blocks/CU via split-K=2 (grid 512; f32 partials).
  gemm_bt<0, 0, 1, 0, 128, 2><<<512, b256, 0, stream>>>(hb, w2b, b2, nullptr, s1, nullptr, M, 1024, 4096);
  ln2_kernel<<<4096, b256, 0, stream>>>(s1, s1 + (size_t)M * 1024, y2, g2, be2, out);

  (void)in_sizes; (void)n_in; (void)out_size; (void)ws_size;
}

// Round 16
// 332.561 us; speedup vs baseline: 1.0414x; 1.0004x over previous
//
#include <hip/hip_runtime.h>
#include <hip/hip_bf16.h>

typedef __attribute__((ext_vector_type(8))) short short8;
typedef __attribute__((ext_vector_type(4))) float f32x4;
typedef __attribute__((ext_vector_type(4))) unsigned short ushort4v;

#define MFMA_BF16(a, b, c) __builtin_amdgcn_mfma_f32_16x16x32_bf16((a), (b), (c), 0, 0, 0)
#define AS1 __attribute__((address_space(1)))
#define AS3 __attribute__((address_space(3)))

__device__ __forceinline__ unsigned short f2b(float f) {
  unsigned u = __float_as_uint(f);
  u += 0x7fffu + ((u >> 16) & 1u);
  return (unsigned short)(u >> 16);
}

// packed-K index: Kp[bh][l][d ^ ((l&7)<<3)]
__device__ __forceinline__ size_t kpack_idx(int row, int col) {
  int b = row >> 10, l = row & 1023, h = col >> 6, d = col & 63;
  return ((size_t)(b * 16 + h) << 16) + l * 64 + (d ^ ((l & 7) << 3));
}

// counted-vmcnt wait [T4]: N newer loads may stay in flight
template <int N>
__device__ __forceinline__ void wait_vm() {
  if constexpr (N == 0) asm volatile("s_waitcnt vmcnt(0)" ::: "memory");
  else if constexpr (N == 6) asm volatile("s_waitcnt vmcnt(6)" ::: "memory");
  else if constexpr (N == 8) asm volatile("s_waitcnt vmcnt(8)" ::: "memory");
  else static_assert(N == 0 || N == 6 || N == 8, "unsupported vmcnt");
}

// ---------------- fused cast f32 -> bf16, 8 segments ----------------
__global__ __launch_bounds__(256) void cast8(
    const float* s0, const float* s1, const float* s2, const float* s3,
    const float* s4, const float* s5, const float* s6, const float* s7,
    unsigned short* d0, unsigned short* d1, unsigned short* d2, unsigned short* d3,
    unsigned short* d4, unsigned short* d5, unsigned short* d6, unsigned short* d7,
    int n0, int n1, int n2, int n3, int n4, int n5, int n6, int n7) {
  const float* s; unsigned short* d; int n;
  switch (blockIdx.y) {
    case 0: s = s0; d = d0; n = n0; break;
    case 1: s = s1; d = d1; n = n1; break;
    case 2: s = s2; d = d2; n = n2; break;
    case 3: s = s3; d = d3; n = n3; break;
    case 4: s = s4; d = d4; n = n4; break;
    case 5: s = s5; d = d5; n = n5; break;
    case 6: s = s6; d = d6; n = n6; break;
    default: s = s7; d = d7; n = n7; break;
  }
  int stride = gridDim.x * blockDim.x;
  for (int i = blockIdx.x * blockDim.x + threadIdx.x; i < n; i += stride) {
    float4 v = reinterpret_cast<const float4*>(s)[i];
    ushort4v o;
    o.x = f2b(v.x); o.y = f2b(v.y); o.z = f2b(v.z); o.w = f2b(v.w);
    reinterpret_cast<ushort4v*>(d)[i] = o;
  }
}

// ------- GEMM: C = A @ W^T (+bias)(+resid)(relu), BK=64, XOR-swizzled ------
// SPLITK=2: grid doubles; half h covers K-range [h*K/2,(h+1)*K/2) writing raw
// f32 partials to outF + h*M*N (bias added by half 0 only; no resid/relu).
template <int RELU, int RES, int OUTF, int OUTB, int TM, int SPLITK>
__global__ __launch_bounds__(256) void gemm_bt(
    const unsigned short* __restrict__ A, const unsigned short* __restrict__ W,
    const float* __restrict__ bias, const float* __restrict__ resid,
    float* __restrict__ outF, unsigned short* __restrict__ outB,
    int M, int N, int K) {
  constexpr int MI = TM / 32;
  __shared__ unsigned short lA[TM * 64];
  __shared__ unsigned short lB[128 * 64];
  int nbn = N >> 7;
  int nwg = gridDim.x;
  int id = blockIdx.x;
  { int q = nwg >> 3; id = (id & 7) * q + (id >> 3); }  // all grids %8 == 0
  int half = 0;
  if (SPLITK == 2) { half = id & 1; id >>= 1; }
  int m0 = (id / nbn) * TM, n0 = (id % nbn) << 7;
  int lane = threadIdx.x & 63, wave = threadIdx.x >> 6;
  int wr = (wave >> 1) * (TM / 2), wc = (wave & 1) * 64;
  int rq = lane & 15, kq = (lane >> 4) * 8;
  int xr8 = (rq & 7) << 3;
  f32x4 acc[MI][4] = {};

  int kBeg = (SPLITK == 2) ? half * (K >> 1) : 0;
  int kEnd = (SPLITK == 2) ? kBeg + (K >> 1) : K;
  int t8 = threadIdx.x * 8;
  for (int kt = kBeg; kt < kEnd; kt += 64) {
#pragma unroll
    for (int i = 0; i < MI; ++i) {  // A: TM*64 elems, MI rounds of 2048
      int e = t8 + i * 2048;
      int row = e >> 6;
      int gcol = (((e >> 3) & 7) ^ (row & 7)) << 3;
      __builtin_amdgcn_global_load_lds(
          (const AS1 void*)(A + (size_t)(m0 + row) * K + kt + gcol),
          (AS3 void*)(lA + e), 16, 0, 0);
    }
#pragma unroll
    for (int i = 0; i < 4; ++i) {  // B: 128*64 elems, 4 rounds
      int e = t8 + i * 2048;
      int row = e >> 6;
      int gcol = (((e >> 3) & 7) ^ (row & 7)) << 3;
      __builtin_amdgcn_global_load_lds(
          (const AS1 void*)(W + (size_t)(n0 + row) * K + kt + gcol),
          (AS3 void*)(lB + e), 16, 0, 0);
    }
    __syncthreads();
#pragma unroll
    for (int s = 0; s < 2; ++s) {
      short8 af[MI], bf[4];
#pragma unroll
      for (int i = 0; i < MI; ++i)
        af[i] = *reinterpret_cast<const short8*>(lA + (wr + i * 16 + rq) * 64 + ((s * 32 + kq) ^ xr8));
#pragma unroll
      for (int j = 0; j < 4; ++j)
        bf[j] = *reinterpret_cast<const short8*>(lB + (wc + j * 16 + rq) * 64 + ((s * 32 + kq) ^ xr8));
#pragma unroll
      for (int i = 0; i < MI; ++i)
#pragma unroll
        for (int j = 0; j < 4; ++j)
          acc[i][j] = MFMA_BF16(af[i], bf[j], acc[i][j]);
    }
    __syncthreads();
  }

  float* outFp = (SPLITK == 2) ? outF + (size_t)half * M * N : outF;
  int r0 = (lane >> 4) * 4;
#pragma unroll
  for (int i = 0; i < MI; ++i) {
#pragma unroll
    for (int j = 0; j < 4; ++j) {
      int row = m0 + wr + i * 16 + r0;
      int col = n0 + wc + j * 16 + rq;
      float bv = (SPLITK == 2 && half) ? 0.0f : bias[col];
#pragma unroll
      for (int r = 0; r < 4; ++r) {
        float v = acc[i][j][r] + bv;
        if (RES) v += resid[(size_t)(row + r) * N + col];
        if (RELU) v = fmaxf(v, 0.0f);
        if (OUTF) outFp[(size_t)(row + r) * N + col] = v;
        if (OUTB) outB[(size_t)(row + r) * N + col] = f2b(v);
      }
    }
  }
}

// ------- fused QKV projections with A-reuse: grid 512, 2 blocks/CU ----------
// Round balance: blocks 0-255 = sel0 (x->QKV), 256-511 = sel1 (enc->KV).
// Counted-vmcnt 2-buf pipeline [T4, TLP-poor regime]: STAGE(t+1) -> vmcnt(N)
// [stage t retired, t+1 in flight] -> barrier -> compute(t) -> barrier.
__global__ __launch_bounds__(256, 2) void gemm_qkv_f(
    const unsigned short* __restrict__ xb, const unsigned short* __restrict__ encb,
    const unsigned short* __restrict__ wq, const unsigned short* __restrict__ wk,
    const unsigned short* __restrict__ wv,
    const float* __restrict__ bq, const float* __restrict__ bk, const float* __restrict__ bv,
    unsigned short* __restrict__ qb, unsigned short* __restrict__ kp1,
    unsigned short* __restrict__ vp1, unsigned short* __restrict__ kp2,
    unsigned short* __restrict__ vp2) {
  __shared__ unsigned short lA[2][4096];
  __shared__ unsigned short lB[2][3][4096];
  int orig = blockIdx.x;           // 512
  int sel = orig >> 8;             // round 0: sel0, round 1: sel1
  int inner = orig & 255;
  inner = (inner & 7) * 32 + (inner >> 3);  // XCD swizzle within round
  int m0 = (inner >> 3) << 7, col0 = (inner & 7) << 7;
  int nW = sel ? 2 : 3;
  const unsigned short* A = sel ? encb : xb;
  const unsigned short* W0 = sel ? wk : wq;
  const unsigned short* W1 = sel ? wv : wk;
  const unsigned short* W2 = wv;
  int lane = threadIdx.x & 63, wave = threadIdx.x >> 6;
  int wr = (wave >> 1) * 64, wc = (wave & 1) * 64;
  int rq = lane & 15, kq = (lane >> 4) * 8;
  int xk = ((rq >> 1) & 3) << 3;  // read-side chunk XOR
  f32x4 acc[3][4][4] = {};

  int e0 = threadIdx.x * 8;
#define STG(KT, BUF)                                                            \
  {                                                                             \
    _Pragma("unroll") for (int i = 0; i < 2; ++i) {                             \
      int e = e0 + i * 2048;                                                    \
      int row = e >> 5;                                                         \
      int gcol = ((((e >> 3) & 3) ^ ((row >> 1) & 3)) << 3);                    \
      __builtin_amdgcn_global_load_lds(                                         \
          (const AS1 void*)(A + (size_t)(m0 + row) * 1024 + (KT) + gcol),       \
          (AS3 void*)(&lA[BUF][e]), 16, 0, 0);                                  \
      __builtin_amdgcn_global_load_lds(                                         \
          (const AS1 void*)(W0 + (size_t)(col0 + row) * 1024 + (KT) + gcol),    \
          (AS3 void*)(&lB[BUF][0][e]), 16, 0, 0);                               \
      __builtin_amdgcn_global_load_lds(                                         \
          (const AS1 void*)(W1 + (size_t)(col0 + row) * 1024 + (KT) + gcol),    \
          (AS3 void*)(&lB[BUF][1][e]), 16, 0, 0);                               \
      if (!sel)                                                                 \
        __builtin_amdgcn_global_load_lds(                                       \
            (const AS1 void*)(W2 + (size_t)(col0 + row) * 1024 + (KT) + gcol),  \
            (AS3 void*)(&lB[BUF][2][e]), 16, 0, 0);                             \
    }                                                                           \
  }

  STG(0, 0);
  for (int t = 0; t < 32; ++t) {
    int cur = t & 1;
    if (t + 1 < 32) {
      STG((t + 1) << 5, cur ^ 1);
      if (sel) wait_vm<6>(); else wait_vm<8>();  // keep t+1's loads in flight
    } else {
      wait_vm<0>();
    }
    __builtin_amdgcn_s_barrier();
    short8 af[4];
#pragma unroll
    for (int i = 0; i < 4; ++i)
      af[i] = *reinterpret_cast<const short8*>(&lA[cur][(wr + i * 16 + rq) * 32 + (kq ^ xk)]);
#pragma unroll
    for (int w = 0; w < 3; ++w) {
      if (w < nW) {
        short8 bf[4];
#pragma unroll
        for (int j = 0; j < 4; ++j)
          bf[j] = *reinterpret_cast<const short8*>(&lB[cur][w][(wc + j * 16 + rq) * 32 + (kq ^ xk)]);
#pragma unroll
        for (int i = 0; i < 4; ++i)
#pragma unroll
          for (int j = 0; j < 4; ++j)
            acc[w][i][j] = MFMA_BF16(af[i], bf[j], acc[w][i][j]);
      }
    }
    __builtin_amdgcn_s_barrier();  // readers of buf[cur] done -> t+1 may overwrite
  }
#undef STG

  int r0 = (lane >> 4) * 4;
#pragma unroll
  for (int w = 0; w < 3; ++w) {
    if (w >= nW) continue;
    const float* bias = sel ? (w == 0 ? bk : bv) : (w == 0 ? bq : (w == 1 ? bk : bv));
    unsigned short* outp = sel ? (w == 0 ? kp2 : vp2) : (w == 0 ? qb : (w == 1 ? kp1 : vp1));
    int pack = sel ? (w + 1) : w;
#pragma unroll
    for (int i = 0; i < 4; ++i) {
#pragma unroll
      for (int j = 0; j < 4; ++j) {
        int row0 = m0 + wr + i * 16 + r0;
        int col = col0 + wc + j * 16 + rq;
        float bv2 = bias[col];
        if (pack == 2) {
          int b = row0 >> 10, k0 = row0 & 1023, h = col >> 6, d = col & 63;
          size_t idx2 = ((size_t)((b * 16 + h) * 16 + (k0 >> 6)) << 12) + d * 64 + ((k0 & 63) ^ ((d & 7) << 3));
          ushort4v o;
          o.x = f2b(acc[w][i][j][0] + bv2);
          o.y = f2b(acc[w][i][j][1] + bv2);
          o.z = f2b(acc[w][i][j][2] + bv2);
          o.w = f2b(acc[w][i][j][3] + bv2);
          *reinterpret_cast<ushort4v*>(&outp[idx2]) = o;
        } else {
#pragma unroll
          for (int r = 0; r < 4; ++r) {
            int row = row0 + r;
            float v = acc[w][i][j][r] + bv2;
            if (pack == 0) outp[(size_t)row * 1024 + col] = f2b(v);
            else outp[kpack_idx(row, col)] = f2b(v);
          }
        }
      }
    }
  }
}

// ---------------- flash attention step (defer-max [T13], THR=4) ----------------
__device__ __forceinline__ void attn_step(
    const unsigned short* __restrict__ kcur, const unsigned short* __restrict__ vcur,
    unsigned short* __restrict__ plw, const short8* qf,
    f32x4* accd, float& m2, float& lsum,
    int rq, int hi, int kq, int xr, int wave, bool domask) {
  const float SC = 0.04508422f;  // (1/sqrt(1024)) * log2(e)
  f32x4 st[4];
  __builtin_amdgcn_s_setprio(1);
#pragma unroll
  for (int sub = 0; sub < 4; ++sub) {
    f32x4 z = {0.f, 0.f, 0.f, 0.f};
#pragma unroll
    for (int c = 0; c < 2; ++c) {
      short8 kf = *reinterpret_cast<const short8*>(
          &kcur[(sub * 16 + rq) * 64 + ((c * 32 + hi * 8) ^ xr)]);
      z = MFMA_BF16(kf, qf[c], z);
    }
    st[sub] = z * SC;
  }
  __builtin_amdgcn_s_setprio(0);
  if (domask) {
#pragma unroll
    for (int sub = 0; sub < 4; ++sub)
#pragma unroll
      for (int r = 0; r < 4; ++r)
        if (sub * 16 + hi * 4 + r > wave * 16 + rq) st[sub][r] = -1e9f;
  }
  f32x4 t0 = {fmaxf(st[0][0], st[1][0]), fmaxf(st[0][1], st[1][1]),
              fmaxf(st[0][2], st[1][2]), fmaxf(st[0][3], st[1][3])};
  f32x4 t1 = {fmaxf(st[2][0], st[3][0]), fmaxf(st[2][1], st[3][1]),
              fmaxf(st[2][2], st[3][2]), fmaxf(st[2][3], st[3][3])};
  float mx = fmaxf(fmaxf(fmaxf(t0[0], t1[0]), fmaxf(t0[1], t1[1])),
                   fmaxf(fmaxf(t0[2], t1[2]), fmaxf(t0[3], t1[3])));
  mx = fmaxf(mx, __shfl_xor(mx, 16, 64));
  mx = fmaxf(mx, __shfl_xor(mx, 32, 64));
  int skip = __all(mx <= m2 + 4.0f);
  float mn = m2, al = 1.0f;
  if (!skip) {
    mn = fmaxf(m2, mx);
    al = exp2f(m2 - mn);
    m2 = mn;
  }
  f32x4 e[4];
#pragma unroll
  for (int sub = 0; sub < 4; ++sub)
#pragma unroll
    for (int r = 0; r < 4; ++r) e[sub][r] = exp2f(st[sub][r] - mn);
  f32x4 s01 = e[0] + e[1], s23 = e[2] + e[3];
  f32x4 s = s01 + s23;
  float ps = (s[0] + s[1]) + (s[2] + s[3]);
  ps += __shfl_xor(ps, 16, 64);
  ps += __shfl_xor(ps, 32, 64);
#pragma unroll
  for (int sub = 0; sub < 4; ++sub) {
    unsigned w0 = (unsigned)f2b(e[sub][0]) | ((unsigned)f2b(e[sub][1]) << 16);
    unsigned w1 = (unsigned)f2b(e[sub][2]) | ((unsigned)f2b(e[sub][3]) << 16);
    uint2 w = make_uint2(w0, w1);
    *reinterpret_cast<uint2*>(&plw[rq * 64 + ((sub * 16 + hi * 4) ^ xr)]) = w;
  }
  if (skip) {
    lsum += ps;
  } else {
    lsum = lsum * al + ps;
    float alb[4];
#pragma unroll
    for (int r = 0; r < 4; ++r) alb[r] = __shfl(al, hi * 4 + r, 64);
#pragma unroll
    for (int d = 0; d < 4; ++d)
#pragma unroll
      for (int r = 0; r < 4; ++r) accd[d][r] *= alb[r];
  }
  short8 pf[2];
#pragma unroll
  for (int c = 0; c < 2; ++c)
    pf[c] = *reinterpret_cast<const short8*>(&plw[rq * 64 + ((c * 32 + hi * 8) ^ xr)]);
  __builtin_amdgcn_s_setprio(1);
#pragma unroll
  for (int d = 0; d < 4; ++d) {
#pragma unroll
    for (int c = 0; c < 2; ++c) {
      short8 vf = *reinterpret_cast<const short8*>(
          &vcur[(d * 16 + rq) * 64 + ((c * 32 + hi * 8) ^ xr)]);
      accd[d] = MFMA_BF16(pf[c], vf, accd[d]);
    }
  }
  __builtin_amdgcn_s_setprio(0);
}

// grid 1024: one q-tile per block -> 4 blocks/CU for TLP.
__global__ __launch_bounds__(256) void attn_kernel(
    const unsigned short* __restrict__ Q, const unsigned short* __restrict__ Kp,
    const unsigned short* __restrict__ Vp, unsigned short* __restrict__ O, int causal) {
  __shared__ unsigned short kls[2][4096];
  __shared__ unsigned short vls[2][4096];
  __shared__ unsigned short pls[4][1024];
  int id = blockIdx.x;
  int xcd = id & 7, rest = id >> 3;
  int qtsel = rest & 15, bhi = rest >> 4;
  int bh = xcd * 8 + bhi;
  int b = bh >> 4, h = bh & 15;
  int qt = causal ? (15 - qtsel) : qtsel;
  int lane = threadIdx.x & 63, wave = threadIdx.x >> 6;
  int rq = lane & 15, hi = lane >> 4, kq = hi * 8;
  int xr = (rq & 7) << 3;
  int sb = wave * 1024 + lane * 8;
  const unsigned short* Kbh = Kp + ((size_t)bh << 16);
  const unsigned short* Vbh = Vp + ((size_t)bh << 16);
  unsigned short* plw = pls[wave];

  int nkt = causal ? (qt + 1) : 16;
  int qrow0 = qt * 64 + wave * 16;
  short8 qf[2];
#pragma unroll
  for (int c = 0; c < 2; ++c)
    qf[c] = *reinterpret_cast<const short8*>(
        Q + (size_t)(b * 1024 + qrow0 + rq) * 1024 + h * 64 + c * 32 + kq);

  float m2 = -1e30f, lsum = 0.f;
  f32x4 accd[4] = {};

#pragma unroll
  for (int i = 0; i < 2; ++i) {
    __builtin_amdgcn_global_load_lds((const AS1 void*)(Kbh + sb + i * 512),
                                     (AS3 void*)(&kls[0][sb + i * 512]), 16, 0, 0);
    __builtin_amdgcn_global_load_lds((const AS1 void*)(Vbh + sb + i * 512),
                                     (AS3 void*)(&vls[0][sb + i * 512]), 16, 0, 0);
  }
  __syncthreads();

  int cur = 0;
  for (int kt = 0; kt < nkt; ++kt) {
    if (kt + 1 < nkt) {
      const unsigned short* kg = Kbh + (kt + 1) * 4096 + sb;
      const unsigned short* vg = Vbh + (kt + 1) * 4096 + sb;
#pragma unroll
      for (int i = 0; i < 2; ++i) {
        __builtin_amdgcn_global_load_lds((const AS1 void*)(kg + i * 512),
                                         (AS3 void*)(&kls[cur ^ 1][sb + i * 512]), 16, 0, 0);
        __builtin_amdgcn_global_load_lds((const AS1 void*)(vg + i * 512),
                                         (AS3 void*)(&vls[cur ^ 1][sb + i * 512]), 16, 0, 0);
      }
    }
    attn_step(kls[cur], vls[cur], plw, qf, accd, m2, lsum, rq, hi, kq, xr, wave,
              causal && kt == qt);
    __syncthreads();
    cur ^= 1;
  }

  float lb[4];
#pragma unroll
  for (int r = 0; r < 4; ++r) lb[r] = 1.0f / __shfl(lsum, hi * 4 + r, 64);
#pragma unroll
  for (int d = 0; d < 4; ++d)
#pragma unroll
    for (int r = 0; r < 4; ++r)
      O[(size_t)(b * 1024 + qrow0 + hi * 4 + r) * 1024 + h * 64 + d * 16 + rq] =
          f2b(accd[d][r] * lb[r]);
}

// ---------------- LayerNorm over 1024 ----------------
template <int OUTF, int OUTB>
__global__ __launch_bounds__(256) void ln_kernel(const float* __restrict__ X,
                                                 const float* __restrict__ g,
                                                 const float* __restrict__ be,
                                                 float* __restrict__ outF,
                                                 unsigned short* __restrict__ outB) {
  __shared__ float red[2][4];
  int row = blockIdx.x;
  int t = threadIdx.x;
  const float* xr = X + (size_t)row * 1024;
  float4 v = reinterpret_cast<const float4*>(xr)[t];
  float s = v.x + v.y + v.z + v.w;
  float ss = v.x * v.x + v.y * v.y + v.z * v.z + v.w * v.w;
#pragma unroll
  for (int off = 1; off < 64; off <<= 1) {
    s += __shfl_xor(s, off, 64);
    ss += __shfl_xor(ss, off, 64);
  }
  int wave = t >> 6;
  if ((t & 63) == 0) { red[0][wave] = s; red[1][wave] = ss; }
  __syncthreads();
  s = red[0][0] + red[0][1] + red[0][2] + red[0][3];
  ss = red[1][0] + red[1][1] + red[1][2] + red[1][3];
  float mu = s * (1.f / 1024.f);
  float var = ss * (1.f / 1024.f) - mu * mu;
  float rs = rsqrtf(var + 1e-5f);
  float4 gv = reinterpret_cast<const float4*>(g)[t];
  float4 bv = reinterpret_cast<const float4*>(be)[t];
  float o0 = (v.x - mu) * rs * gv.x + bv.x;
  float o1 = (v.y - mu) * rs * gv.y + bv.y;
  float o2 = (v.z - mu) * rs * gv.z + bv.z;
  float o3 = (v.w - mu) * rs * gv.w + bv.w;
  if (OUTF) {
    float4 o = make_float4(o0, o1, o2, o3);
    reinterpret_cast<float4*>(outF + (size_t)row * 1024)[t] = o;
  }
  if (OUTB) {
    ushort4v o;
    o.x = f2b(o0); o.y = f2b(o1); o.z = f2b(o2); o.w = f2b(o3);
    reinterpret_cast<ushort4v*>(outB + (size_t)row * 1024)[t] = o;
  }
}

// ---- final LayerNorm over (a + b + resid): consumes split-K partials ----
__global__ __launch_bounds__(256) void ln2_kernel(const float* __restrict__ Xa,
                                                  const float* __restrict__ Xb,
                                                  const float* __restrict__ R,
                                                  const float* __restrict__ g,
                                                  const float* __restrict__ be,
                                                  float* __restrict__ outF) {
  __shared__ float red[2][4];
  int row = blockIdx.x;
  int t = threadIdx.x;
  float4 va = reinterpret_cast<const float4*>(Xa + (size_t)row * 1024)[t];
  float4 vb = reinterpret_cast<const float4*>(Xb + (size_t)row * 1024)[t];
  float4 vr = reinterpret_cast<const float4*>(R + (size_t)row * 1024)[t];
  float4 v = make_float4(va.x + vb.x + vr.x, va.y + vb.y + vr.y,
                         va.z + vb.z + vr.z, va.w + vb.w + vr.w);
  float s = v.x + v.y + v.z + v.w;
  float ss = v.x * v.x + v.y * v.y + v.z * v.z + v.w * v.w;
#pragma unroll
  for (int off = 1; off < 64; off <<= 1) {
    s += __shfl_xor(s, off, 64);
    ss += __shfl_xor(ss, off, 64);
  }
  int wave = t >> 6;
  if ((t & 63) == 0) { red[0][wave] = s; red[1][wave] = ss; }
  __syncthreads();
  s = red[0][0] + red[0][1] + red[0][2] + red[0][3];
  ss = red[1][0] + red[1][1] + red[1][2] + red[1][3];
  float mu = s * (1.f / 1024.f);
  float var = ss * (1.f / 1024.f) - mu * mu;
  float rs = rsqrtf(var + 1e-5f);
  float4 gv = reinterpret_cast<const float4*>(g)[t];
  float4 bv = reinterpret_cast<const float4*>(be)[t];
  float4 o = make_float4((v.x - mu) * rs * gv.x + bv.x, (v.y - mu) * rs * gv.y + bv.y,
                         (v.z - mu) * rs * gv.z + bv.z, (v.w - mu) * rs * gv.w + bv.w);
  reinterpret_cast<float4*>(outF + (size_t)row * 1024)[t] = o;
}

extern "C" void kernel_launch(void* const* d_in, const int* in_sizes, int n_in,
                              void* d_out, int out_size, void* d_ws, size_t ws_size,
                              hipStream_t stream) {
  const float* x   = (const float*)d_in[0];
  const float* enc = (const float*)d_in[1];
  const float* wq = (const float*)d_in[4];  const float* bq = (const float*)d_in[5];
  const float* wk = (const float*)d_in[6];  const float* bk = (const float*)d_in[7];
  const float* wv = (const float*)d_in[8];  const float* bv = (const float*)d_in[9];
  const float* wo = (const float*)d_in[10]; const float* bo = (const float*)d_in[11];
  const float* w1 = (const float*)d_in[12]; const float* b1 = (const float*)d_in[13];
  const float* w2 = (const float*)d_in[14]; const float* b2 = (const float*)d_in[15];
  const float* g1 = (const float*)d_in[16]; const float* be1 = (const float*)d_in[17];
  const float* g2 = (const float*)d_in[18]; const float* be2 = (const float*)d_in[19];
  float* out = (float*)d_out;

  const int M = 4096;  // B*L
  char* ws = (char*)d_ws;
  size_t off = 0;
  auto alloc = [&](size_t bytes) -> char* {
    char* p = ws + off;
    off += (bytes + 255) & ~(size_t)255;
    return p;
  };
  unsigned short* xb   = (unsigned short*)alloc((size_t)M * 1024 * 2);
  unsigned short* encb = (unsigned short*)alloc((size_t)M * 1024 * 2);
  unsigned short* wqb  = (unsigned short*)alloc((size_t)1024 * 1024 * 2);
  unsigned short* wkb  = (unsigned short*)alloc((size_t)1024 * 1024 * 2);
  unsigned short* wvb  = (unsigned short*)alloc((size_t)1024 * 1024 * 2);
  unsigned short* wob  = (unsigned short*)alloc((size_t)1024 * 1024 * 2);
  unsigned short* w1b  = (unsigned short*)alloc((size_t)4096 * 1024 * 2);
  unsigned short* w2b  = (unsigned short*)alloc((size_t)4096 * 1024 * 2);
  unsigned short* qb   = (unsigned short*)alloc((size_t)M * 1024 * 2);
  unsigned short* kp1  = (unsigned short*)alloc((size_t)M * 1024 * 2);  // contiguous group:
  unsigned short* vp1  = (unsigned short*)alloc((size_t)M * 1024 * 2);  //   aliased by hb
  unsigned short* kp2  = (unsigned short*)alloc((size_t)M * 1024 * 2);
  unsigned short* vp2  = (unsigned short*)alloc((size_t)M * 1024 * 2);
  unsigned short* ab   = (unsigned short*)alloc((size_t)M * 1024 * 2);
  float* s1 = (float*)alloc((size_t)2 * M * 1024 * 4);  // 2 halves for split-K
  float* y1 = (float*)alloc((size_t)M * 1024 * 4);
  unsigned short* hb = kp1;  // 32MB: kp1..vp2 all dead after attn2
  unsigned short* y1b = xb;  // xb dead after gemm_qkv_f
  unsigned short* y2b = qb;  // qb dead after attn2
  float* y2 = y1;            // y1 dead after O2 projection

  dim3 b256(256);
  cast8<<<dim3(256, 8), b256, 0, stream>>>(
      x, enc, wq, wk, wv, wo, w1, w2,
      xb, encb, wqb, wkb, wvb, wob, w1b, w2b,
      M * 1024 / 4, M * 1024 / 4, 262144, 262144, 262144, 262144,
      4096 * 1024 / 4, 4096 * 1024 / 4);

  // ---- all input-dependent projections in one launch (A-reuse fused) ----
  gemm_qkv_f<<<512, b256, 0, stream>>>(xb, encb, wqb, wkb, wvb, bq, bk, bv,
                                       qb, kp1, vp1, kp2, vp2);

  // ---- self attention ----
  attn_kernel<<<1024, b256, 0, stream>>>(qb, kp1, vp1, ab, 1);
  gemm_bt<0, 1, 1, 0, 64, 1><<<512, b256, 0, stream>>>(ab, wob, bo, x, s1, nullptr, M, 1024, 1024);
  ln_kernel<1, 1><<<4096, b256, 0, stream>>>(s1, g1, be1, y1, y1b);

  // ---- cross attention ----
  gemm_bt<0, 0, 0, 1, 64, 1><<<512, b256, 0, stream>>>(y1b, wqb, bq, nullptr, nullptr, qb, M, 1024, 1024);
  attn_kernel<<<1024, b256, 0, stream>>>(qb, kp2, vp2, ab, 0);
  gemm_bt<0, 1, 1, 0, 64, 1><<<512, b256, 0, stream>>>(ab, wob, bo, y1, s1, nullptr, M, 1024, 1024);
  ln_kernel<1, 1><<<4096, b256, 0, stream>>>(s1, g1, be1, y2, y2b);

  // ---- FFN ----
  gemm_bt<1, 0, 0, 1, 128, 1><<<1024, b256, 0, stream>>>(y2b, w1b, b1, nullptr, nullptr, hb, M, 4096, 1024);
  // FFN2: TM=128 tile at 2 blocks/CU via split-K=2 (grid 512; f32 partials).
  gemm_bt<0, 0, 1, 0, 128, 2><<<512, b256, 0, stream>>>(hb, w2b, b2, nullptr, s1, nullptr, M, 1024, 4096);
  ln2_kernel<<<4096, b256, 0, stream>>>(s1, s1 + (size_t)M * 1024, y2, g2, be2, out);

  (void)in_sizes; (void)n_in; (void)out_size; (void)ws_size;
}

// Round 17
// 330.393 us; speedup vs baseline: 1.0482x; 1.0066x over previous
//
#include <hip/hip_runtime.h>
#include <hip/hip_bf16.h>

typedef __attribute__((ext_vector_type(8))) short short8;
typedef __attribute__((ext_vector_type(4))) float f32x4;
typedef __attribute__((ext_vector_type(4))) unsigned short ushort4v;

#define MFMA_BF16(a, b, c) __builtin_amdgcn_mfma_f32_16x16x32_bf16((a), (b), (c), 0, 0, 0)
#define AS1 __attribute__((address_space(1)))
#define AS3 __attribute__((address_space(3)))

__device__ __forceinline__ unsigned short f2b(float f) {
  unsigned u = __float_as_uint(f);
  u += 0x7fffu + ((u >> 16) & 1u);
  return (unsigned short)(u >> 16);
}

// packed-K index: Kp[bh][l][d ^ ((l&7)<<3)]
__device__ __forceinline__ size_t kpack_idx(int row, int col) {
  int b = row >> 10, l = row & 1023, h = col >> 6, d = col & 63;
  return ((size_t)(b * 16 + h) << 16) + l * 64 + (d ^ ((l & 7) << 3));
}

// counted-vmcnt wait [T4]: N newer loads may stay in flight
template <int N>
__device__ __forceinline__ void wait_vm() {
  if constexpr (N == 0) asm volatile("s_waitcnt vmcnt(0)" ::: "memory");
  else if constexpr (N == 6) asm volatile("s_waitcnt vmcnt(6)" ::: "memory");
  else if constexpr (N == 8) asm volatile("s_waitcnt vmcnt(8)" ::: "memory");
  else static_assert(N == 0 || N == 6 || N == 8, "unsupported vmcnt");
}

// ---------------- fused cast f32 -> bf16, 8 segments ----------------
__global__ __launch_bounds__(256) void cast8(
    const float* s0, const float* s1, const float* s2, const float* s3,
    const float* s4, const float* s5, const float* s6, const float* s7,
    unsigned short* d0, unsigned short* d1, unsigned short* d2, unsigned short* d3,
    unsigned short* d4, unsigned short* d5, unsigned short* d6, unsigned short* d7,
    int n0, int n1, int n2, int n3, int n4, int n5, int n6, int n7) {
  const float* s; unsigned short* d; int n;
  switch (blockIdx.y) {
    case 0: s = s0; d = d0; n = n0; break;
    case 1: s = s1; d = d1; n = n1; break;
    case 2: s = s2; d = d2; n = n2; break;
    case 3: s = s3; d = d3; n = n3; break;
    case 4: s = s4; d = d4; n = n4; break;
    case 5: s = s5; d = d5; n = n5; break;
    case 6: s = s6; d = d6; n = n6; break;
    default: s = s7; d = d7; n = n7; break;
  }
  int stride = gridDim.x * blockDim.x;
  for (int i = blockIdx.x * blockDim.x + threadIdx.x; i < n; i += stride) {
    float4 v = reinterpret_cast<const float4*>(s)[i];
    ushort4v o;
    o.x = f2b(v.x); o.y = f2b(v.y); o.z = f2b(v.z); o.w = f2b(v.w);
    reinterpret_cast<ushort4v*>(d)[i] = o;
  }
}

// ------- GEMM: C = A @ W^T (+bias)(+resid)(relu), BK=64, XOR-swizzled ------
// SPLITK=2: grid doubles; half h covers K-range [h*K/2,(h+1)*K/2) writing raw
// f32 partials to outF + h*M*N (bias added by half 0 only; no resid/relu).
template <int RELU, int RES, int OUTF, int OUTB, int TM, int SPLITK>
__global__ __launch_bounds__(256) void gemm_bt(
    const unsigned short* __restrict__ A, const unsigned short* __restrict__ W,
    const float* __restrict__ bias, const float* __restrict__ resid,
    float* __restrict__ outF, unsigned short* __restrict__ outB,
    int M, int N, int K) {
  constexpr int MI = TM / 32;
  __shared__ unsigned short lA[TM * 64];
  __shared__ unsigned short lB[128 * 64];
  int nbn = N >> 7;
  int nwg = gridDim.x;
  int id = blockIdx.x;
  { int q = nwg >> 3; id = (id & 7) * q + (id >> 3); }  // all grids %8 == 0
  int half = 0;
  if (SPLITK == 2) { half = id & 1; id >>= 1; }
  int m0 = (id / nbn) * TM, n0 = (id % nbn) << 7;
  int lane = threadIdx.x & 63, wave = threadIdx.x >> 6;
  int wr = (wave >> 1) * (TM / 2), wc = (wave & 1) * 64;
  int rq = lane & 15, kq = (lane >> 4) * 8;
  int xr8 = (rq & 7) << 3;
  f32x4 acc[MI][4] = {};

  int kBeg = (SPLITK == 2) ? half * (K >> 1) : 0;
  int kEnd = (SPLITK == 2) ? kBeg + (K >> 1) : K;
  int t8 = threadIdx.x * 8;
  for (int kt = kBeg; kt < kEnd; kt += 64) {
#pragma unroll
    for (int i = 0; i < MI; ++i) {  // A: TM*64 elems, MI rounds of 2048
      int e = t8 + i * 2048;
      int row = e >> 6;
      int gcol = (((e >> 3) & 7) ^ (row & 7)) << 3;
      __builtin_amdgcn_global_load_lds(
          (const AS1 void*)(A + (size_t)(m0 + row) * K + kt + gcol),
          (AS3 void*)(lA + e), 16, 0, 0);
    }
#pragma unroll
    for (int i = 0; i < 4; ++i) {  // B: 128*64 elems, 4 rounds
      int e = t8 + i * 2048;
      int row = e >> 6;
      int gcol = (((e >> 3) & 7) ^ (row & 7)) << 3;
      __builtin_amdgcn_global_load_lds(
          (const AS1 void*)(W + (size_t)(n0 + row) * K + kt + gcol),
          (AS3 void*)(lB + e), 16, 0, 0);
    }
    __syncthreads();
#pragma unroll
    for (int s = 0; s < 2; ++s) {
      short8 af[MI], bf[4];
#pragma unroll
      for (int i = 0; i < MI; ++i)
        af[i] = *reinterpret_cast<const short8*>(lA + (wr + i * 16 + rq) * 64 + ((s * 32 + kq) ^ xr8));
#pragma unroll
      for (int j = 0; j < 4; ++j)
        bf[j] = *reinterpret_cast<const short8*>(lB + (wc + j * 16 + rq) * 64 + ((s * 32 + kq) ^ xr8));
#pragma unroll
      for (int i = 0; i < MI; ++i)
#pragma unroll
        for (int j = 0; j < 4; ++j)
          acc[i][j] = MFMA_BF16(af[i], bf[j], acc[i][j]);
    }
    __syncthreads();
  }

  float* outFp = (SPLITK == 2) ? outF + (size_t)half * M * N : outF;
  int r0 = (lane >> 4) * 4;
#pragma unroll
  for (int i = 0; i < MI; ++i) {
#pragma unroll
    for (int j = 0; j < 4; ++j) {
      int row = m0 + wr + i * 16 + r0;
      int col = n0 + wc + j * 16 + rq;
      float bv = (SPLITK == 2 && half) ? 0.0f : bias[col];
#pragma unroll
      for (int r = 0; r < 4; ++r) {
        float v = acc[i][j][r] + bv;
        if (RES) v += resid[(size_t)(row + r) * N + col];
        if (RELU) v = fmaxf(v, 0.0f);
        if (OUTF) outFp[(size_t)(row + r) * N + col] = v;
        if (OUTB) outB[(size_t)(row + r) * N + col] = f2b(v);
      }
    }
  }
}

// ------- fused QKV projections with A-reuse: grid 512, 2 blocks/CU ----------
// Round balance: blocks 0-255 = sel0 (x->QKV), 256-511 = sel1 (enc->KV).
// Counted-vmcnt 2-buf pipeline: STAGE(t+1) -> vmcnt(N) -> barrier -> compute.
__global__ __launch_bounds__(256, 2) void gemm_qkv_f(
    const unsigned short* __restrict__ xb, const unsigned short* __restrict__ encb,
    const unsigned short* __restrict__ wq, const unsigned short* __restrict__ wk,
    const unsigned short* __restrict__ wv,
    const float* __restrict__ bq, const float* __restrict__ bk, const float* __restrict__ bv,
    unsigned short* __restrict__ qb, unsigned short* __restrict__ kp1,
    unsigned short* __restrict__ vp1, unsigned short* __restrict__ kp2,
    unsigned short* __restrict__ vp2) {
  __shared__ unsigned short lA[2][4096];
  __shared__ unsigned short lB[2][3][4096];
  int orig = blockIdx.x;           // 512
  int sel = orig >> 8;             // round 0: sel0, round 1: sel1
  int inner = orig & 255;
  inner = (inner & 7) * 32 + (inner >> 3);  // XCD swizzle within round
  int m0 = (inner >> 3) << 7, col0 = (inner & 7) << 7;
  int nW = sel ? 2 : 3;
  const unsigned short* A = sel ? encb : xb;
  const unsigned short* W0 = sel ? wk : wq;
  const unsigned short* W1 = sel ? wv : wk;
  const unsigned short* W2 = wv;
  int lane = threadIdx.x & 63, wave = threadIdx.x >> 6;
  int wr = (wave >> 1) * 64, wc = (wave & 1) * 64;
  int rq = lane & 15, kq = (lane >> 4) * 8;
  int xk = ((rq >> 1) & 3) << 3;  // read-side chunk XOR
  f32x4 acc[3][4][4] = {};

  int e0 = threadIdx.x * 8;
#define STG(KT, BUF)                                                            \
  {                                                                             \
    _Pragma("unroll") for (int i = 0; i < 2; ++i) {                             \
      int e = e0 + i * 2048;                                                    \
      int row = e >> 5;                                                         \
      int gcol = ((((e >> 3) & 3) ^ ((row >> 1) & 3)) << 3);                    \
      __builtin_amdgcn_global_load_lds(                                         \
          (const AS1 void*)(A + (size_t)(m0 + row) * 1024 + (KT) + gcol),       \
          (AS3 void*)(&lA[BUF][e]), 16, 0, 0);                                  \
      __builtin_amdgcn_global_load_lds(                                         \
          (const AS1 void*)(W0 + (size_t)(col0 + row) * 1024 + (KT) + gcol),    \
          (AS3 void*)(&lB[BUF][0][e]), 16, 0, 0);                               \
      __builtin_amdgcn_global_load_lds(                                         \
          (const AS1 void*)(W1 + (size_t)(col0 + row) * 1024 + (KT) + gcol),    \
          (AS3 void*)(&lB[BUF][1][e]), 16, 0, 0);                               \
      if (!sel)                                                                 \
        __builtin_amdgcn_global_load_lds(                                       \
            (const AS1 void*)(W2 + (size_t)(col0 + row) * 1024 + (KT) + gcol),  \
            (AS3 void*)(&lB[BUF][2][e]), 16, 0, 0);                             \
    }                                                                           \
  }

  STG(0, 0);
  for (int t = 0; t < 32; ++t) {
    int cur = t & 1;
    if (t + 1 < 32) {
      STG((t + 1) << 5, cur ^ 1);
      if (sel) wait_vm<6>(); else wait_vm<8>();  // keep t+1's loads in flight
    } else {
      wait_vm<0>();
    }
    __builtin_amdgcn_s_barrier();
    short8 af[4];
#pragma unroll
    for (int i = 0; i < 4; ++i)
      af[i] = *reinterpret_cast<const short8*>(&lA[cur][(wr + i * 16 + rq) * 32 + (kq ^ xk)]);
#pragma unroll
    for (int w = 0; w < 3; ++w) {
      if (w < nW) {
        short8 bf[4];
#pragma unroll
        for (int j = 0; j < 4; ++j)
          bf[j] = *reinterpret_cast<const short8*>(&lB[cur][w][(wc + j * 16 + rq) * 32 + (kq ^ xk)]);
#pragma unroll
        for (int i = 0; i < 4; ++i)
#pragma unroll
          for (int j = 0; j < 4; ++j)
            acc[w][i][j] = MFMA_BF16(af[i], bf[j], acc[w][i][j]);
      }
    }
    __builtin_amdgcn_s_barrier();  // readers of buf[cur] done -> t+1 may overwrite
  }
#undef STG

  int r0 = (lane >> 4) * 4;
#pragma unroll
  for (int w = 0; w < 3; ++w) {
    if (w >= nW) continue;
    const float* bias = sel ? (w == 0 ? bk : bv) : (w == 0 ? bq : (w == 1 ? bk : bv));
    unsigned short* outp = sel ? (w == 0 ? kp2 : vp2) : (w == 0 ? qb : (w == 1 ? kp1 : vp1));
    int pack = sel ? (w + 1) : w;
#pragma unroll
    for (int i = 0; i < 4; ++i) {
#pragma unroll
      for (int j = 0; j < 4; ++j) {
        int row0 = m0 + wr + i * 16 + r0;
        int col = col0 + wc + j * 16 + rq;
        float bv2 = bias[col];
        if (pack == 2) {
          int b = row0 >> 10, k0 = row0 & 1023, h = col >> 6, d = col & 63;
          size_t idx2 = ((size_t)((b * 16 + h) * 16 + (k0 >> 6)) << 12) + d * 64 + ((k0 & 63) ^ ((d & 7) << 3));
          ushort4v o;
          o.x = f2b(acc[w][i][j][0] + bv2);
          o.y = f2b(acc[w][i][j][1] + bv2);
          o.z = f2b(acc[w][i][j][2] + bv2);
          o.w = f2b(acc[w][i][j][3] + bv2);
          *reinterpret_cast<ushort4v*>(&outp[idx2]) = o;
        } else {
#pragma unroll
          for (int r = 0; r < 4; ++r) {
            int row = row0 + r;
            float v = acc[w][i][j][r] + bv2;
            if (pack == 0) outp[(size_t)row * 1024 + col] = f2b(v);
            else outp[kpack_idx(row, col)] = f2b(v);
          }
        }
      }
    }
  }
}

// ---------------- flash attention: 32KB LDS (5 blocks/CU), split-barrier ----
// Per iter: V(t+1)-stage -> QK^T(kls) -> raw s_barrier [kls reads retired via
// MFMA data-dep waits; V DMA stays in flight] -> K(t+1)-stage into kls ->
// softmax+PV(vls[cur]) -> __syncthreads [drains both DMAs]. K latency hides
// under softmax+PV; V latency under QK^T. Defer-max [T13] THR=4.
__global__ __launch_bounds__(256) void attn_kernel(
    const unsigned short* __restrict__ Q, const unsigned short* __restrict__ Kp,
    const unsigned short* __restrict__ Vp, unsigned short* __restrict__ O, int causal) {
  __shared__ unsigned short kls[4096];      // single-buffered K (8KB)
  __shared__ unsigned short vls[2][4096];   // double-buffered V (16KB)
  __shared__ unsigned short pls[4][1024];   // per-wave P (8KB)
  const float SC = 0.04508422f;  // (1/sqrt(1024)) * log2(e)
  int id = blockIdx.x;
  int xcd = id & 7, rest = id >> 3;
  int qtsel = rest & 15, bhi = rest >> 4;
  int bh = xcd * 8 + bhi;
  int b = bh >> 4, h = bh & 15;
  int qt = causal ? (15 - qtsel) : qtsel;
  int lane = threadIdx.x & 63, wave = threadIdx.x >> 6;
  int rq = lane & 15, hi = lane >> 4, kq = hi * 8;
  int xr = (rq & 7) << 3;
  int sb = wave * 1024 + lane * 8;
  const unsigned short* Kbh = Kp + ((size_t)bh << 16);
  const unsigned short* Vbh = Vp + ((size_t)bh << 16);
  unsigned short* plw = pls[wave];

  int nkt = causal ? (qt + 1) : 16;
  int qrow0 = qt * 64 + wave * 16;
  short8 qf[2];
#pragma unroll
  for (int c = 0; c < 2; ++c)
    qf[c] = *reinterpret_cast<const short8*>(
        Q + (size_t)(b * 1024 + qrow0 + rq) * 1024 + h * 64 + c * 32 + kq);

  float m2 = -1e30f, lsum = 0.f;
  f32x4 accd[4] = {};

#pragma unroll
  for (int i = 0; i < 2; ++i) {
    __builtin_amdgcn_global_load_lds((const AS1 void*)(Kbh + sb + i * 512),
                                     (AS3 void*)(&kls[sb + i * 512]), 16, 0, 0);
    __builtin_amdgcn_global_load_lds((const AS1 void*)(Vbh + sb + i * 512),
                                     (AS3 void*)(&vls[0][sb + i * 512]), 16, 0, 0);
  }
  __syncthreads();

  for (int kt = 0; kt < nkt; ++kt) {
    int cur = kt & 1;
    if (kt + 1 < nkt) {  // stage next V (latency hides under QK^T)
      const unsigned short* vg = Vbh + (kt + 1) * 4096 + sb;
#pragma unroll
      for (int i = 0; i < 2; ++i)
        __builtin_amdgcn_global_load_lds((const AS1 void*)(vg + i * 512),
                                         (AS3 void*)(&vls[cur ^ 1][sb + i * 512]), 16, 0, 0);
    }
    // ---- QK^T from kls (swapped: lane holds 16 scores of q-row rq) ----
    f32x4 st[4];
    __builtin_amdgcn_s_setprio(1);
#pragma unroll
    for (int sub = 0; sub < 4; ++sub) {
      f32x4 z = {0.f, 0.f, 0.f, 0.f};
#pragma unroll
      for (int c = 0; c < 2; ++c) {
        short8 kf = *reinterpret_cast<const short8*>(
            &kls[(sub * 16 + rq) * 64 + ((c * 32 + hi * 8) ^ xr)]);
        z = MFMA_BF16(kf, qf[c], z);
      }
      st[sub] = z * SC;
    }
    __builtin_amdgcn_s_setprio(0);
    // barrier-A: all waves' kls reads retired (data-dep lgkm waits before the
    // MFMAs above); raw barrier leaves the V(t+1) DMA in flight.
    __builtin_amdgcn_s_barrier();
    __builtin_amdgcn_sched_barrier(0);
    if (kt + 1 < nkt) {  // overwrite kls with K(t+1); latency hides below
      const unsigned short* kg = Kbh + (kt + 1) * 4096 + sb;
#pragma unroll
      for (int i = 0; i < 2; ++i)
        __builtin_amdgcn_global_load_lds((const AS1 void*)(kg + i * 512),
                                         (AS3 void*)(&kls[sb + i * 512]), 16, 0, 0);
    }
    // ---- softmax (defer-max) + PV ----
    if (causal && kt == qt) {
#pragma unroll
      for (int sub = 0; sub < 4; ++sub)
#pragma unroll
        for (int r = 0; r < 4; ++r)
          if (sub * 16 + hi * 4 + r > wave * 16 + rq) st[sub][r] = -1e9f;
    }
    f32x4 t0 = {fmaxf(st[0][0], st[1][0]), fmaxf(st[0][1], st[1][1]),
                fmaxf(st[0][2], st[1][2]), fmaxf(st[0][3], st[1][3])};
    f32x4 t1 = {fmaxf(st[2][0], st[3][0]), fmaxf(st[2][1], st[3][1]),
                fmaxf(st[2][2], st[3][2]), fmaxf(st[2][3], st[3][3])};
    float mx = fmaxf(fmaxf(fmaxf(t0[0], t1[0]), fmaxf(t0[1], t1[1])),
                     fmaxf(fmaxf(t0[2], t1[2]), fmaxf(t0[3], t1[3])));
    mx = fmaxf(mx, __shfl_xor(mx, 16, 64));
    mx = fmaxf(mx, __shfl_xor(mx, 32, 64));
    int skip = __all(mx <= m2 + 4.0f);
    float mn = m2, al = 1.0f;
    if (!skip) {
      mn = fmaxf(m2, mx);
      al = exp2f(m2 - mn);
      m2 = mn;
    }
    f32x4 e[4];
#pragma unroll
    for (int sub = 0; sub < 4; ++sub)
#pragma unroll
      for (int r = 0; r < 4; ++r) e[sub][r] = exp2f(st[sub][r] - mn);
    f32x4 s01 = e[0] + e[1], s23 = e[2] + e[3];
    f32x4 s = s01 + s23;
    float ps = (s[0] + s[1]) + (s[2] + s[3]);
    ps += __shfl_xor(ps, 16, 64);
    ps += __shfl_xor(ps, 32, 64);
#pragma unroll
    for (int sub = 0; sub < 4; ++sub) {
      unsigned w0 = (unsigned)f2b(e[sub][0]) | ((unsigned)f2b(e[sub][1]) << 16);
      unsigned w1 = (unsigned)f2b(e[sub][2]) | ((unsigned)f2b(e[sub][3]) << 16);
      uint2 w = make_uint2(w0, w1);
      *reinterpret_cast<uint2*>(&plw[rq * 64 + ((sub * 16 + hi * 4) ^ xr)]) = w;
    }
    if (skip) {
      lsum += ps;
    } else {
      lsum = lsum * al + ps;
      float alb[4];
#pragma unroll
      for (int r = 0; r < 4; ++r) alb[r] = __shfl(al, hi * 4 + r, 64);
#pragma unroll
      for (int d = 0; d < 4; ++d)
#pragma unroll
        for (int r = 0; r < 4; ++r) accd[d][r] *= alb[r];
    }
    short8 pf[2];
#pragma unroll
    for (int c = 0; c < 2; ++c)
      pf[c] = *reinterpret_cast<const short8*>(&plw[rq * 64 + ((c * 32 + hi * 8) ^ xr)]);
    __builtin_amdgcn_s_setprio(1);
#pragma unroll
    for (int d = 0; d < 4; ++d) {
#pragma unroll
      for (int c = 0; c < 2; ++c) {
        short8 vf = *reinterpret_cast<const short8*>(
            &vls[cur][(d * 16 + rq) * 64 + ((c * 32 + hi * 8) ^ xr)]);
        accd[d] = MFMA_BF16(pf[c], vf, accd[d]);
      }
    }
    __builtin_amdgcn_s_setprio(0);
    __syncthreads();  // barrier-B: drains K/V DMAs; all done with vls[cur]
  }

  float lb[4];
#pragma unroll
  for (int r = 0; r < 4; ++r) lb[r] = 1.0f / __shfl(lsum, hi * 4 + r, 64);
#pragma unroll
  for (int d = 0; d < 4; ++d)
#pragma unroll
    for (int r = 0; r < 4; ++r)
      O[(size_t)(b * 1024 + qrow0 + hi * 4 + r) * 1024 + h * 64 + d * 16 + rq] =
          f2b(accd[d][r] * lb[r]);
}

// ---------------- LayerNorm over 1024 ----------------
template <int OUTF, int OUTB>
__global__ __launch_bounds__(256) void ln_kernel(const float* __restrict__ X,
                                                 const float* __restrict__ g,
                                                 const float* __restrict__ be,
                                                 float* __restrict__ outF,
                                                 unsigned short* __restrict__ outB) {
  __shared__ float red[2][4];
  int row = blockIdx.x;
  int t = threadIdx.x;
  const float* xr = X + (size_t)row * 1024;
  float4 v = reinterpret_cast<const float4*>(xr)[t];
  float s = v.x + v.y + v.z + v.w;
  float ss = v.x * v.x + v.y * v.y + v.z * v.z + v.w * v.w;
#pragma unroll
  for (int off = 1; off < 64; off <<= 1) {
    s += __shfl_xor(s, off, 64);
    ss += __shfl_xor(ss, off, 64);
  }
  int wave = t >> 6;
  if ((t & 63) == 0) { red[0][wave] = s; red[1][wave] = ss; }
  __syncthreads();
  s = red[0][0] + red[0][1] + red[0][2] + red[0][3];
  ss = red[1][0] + red[1][1] + red[1][2] + red[1][3];
  float mu = s * (1.f / 1024.f);
  float var = ss * (1.f / 1024.f) - mu * mu;
  float rs = rsqrtf(var + 1e-5f);
  float4 gv = reinterpret_cast<const float4*>(g)[t];
  float4 bv = reinterpret_cast<const float4*>(be)[t];
  float o0 = (v.x - mu) * rs * gv.x + bv.x;
  float o1 = (v.y - mu) * rs * gv.y + bv.y;
  float o2 = (v.z - mu) * rs * gv.z + bv.z;
  float o3 = (v.w - mu) * rs * gv.w + bv.w;
  if (OUTF) {
    float4 o = make_float4(o0, o1, o2, o3);
    reinterpret_cast<float4*>(outF + (size_t)row * 1024)[t] = o;
  }
  if (OUTB) {
    ushort4v o;
    o.x = f2b(o0); o.y = f2b(o1); o.z = f2b(o2); o.w = f2b(o3);
    reinterpret_cast<ushort4v*>(outB + (size_t)row * 1024)[t] = o;
  }
}

// ---- final LayerNorm over (a + b + resid): consumes split-K partials ----
__global__ __launch_bounds__(256) void ln2_kernel(const float* __restrict__ Xa,
                                                  const float* __restrict__ Xb,
                                                  const float* __restrict__ R,
                                                  const float* __restrict__ g,
                                                  const float* __restrict__ be,
                                                  float* __restrict__ outF) {
  __shared__ float red[2][4];
  int row = blockIdx.x;
  int t = threadIdx.x;
  float4 va = reinterpret_cast<const float4*>(Xa + (size_t)row * 1024)[t];
  float4 vb = reinterpret_cast<const float4*>(Xb + (size_t)row * 1024)[t];
  float4 vr = reinterpret_cast<const float4*>(R + (size_t)row * 1024)[t];
  float4 v = make_float4(va.x + vb.x + vr.x, va.y + vb.y + vr.y,
                         va.z + vb.z + vr.z, va.w + vb.w + vr.w);
  float s = v.x + v.y + v.z + v.w;
  float ss = v.x * v.x + v.y * v.y + v.z * v.z + v.w * v.w;
#pragma unroll
  for (int off = 1; off < 64; off <<= 1) {
    s += __shfl_xor(s, off, 64);
    ss += __shfl_xor(ss, off, 64);
  }
  int wave = t >> 6;
  if ((t & 63) == 0) { red[0][wave] = s; red[1][wave] = ss; }
  __syncthreads();
  s = red[0][0] + red[0][1] + red[0][2] + red[0][3];
  ss = red[1][0] + red[1][1] + red[1][2] + red[1][3];
  float mu = s * (1.f / 1024.f);
  float var = ss * (1.f / 1024.f) - mu * mu;
  float rs = rsqrtf(var + 1e-5f);
  float4 gv = reinterpret_cast<const float4*>(g)[t];
  float4 bv = reinterpret_cast<const float4*>(be)[t];
  float4 o = make_float4((v.x - mu) * rs * gv.x + bv.x, (v.y - mu) * rs * gv.y + bv.y,
                         (v.z - mu) * rs * gv.z + bv.z, (v.w - mu) * rs * gv.w + bv.w);
  reinterpret_cast<float4*>(outF + (size_t)row * 1024)[t] = o;
}

extern "C" void kernel_launch(void* const* d_in, const int* in_sizes, int n_in,
                              void* d_out, int out_size, void* d_ws, size_t ws_size,
                              hipStream_t stream) {
  const float* x   = (const float*)d_in[0];
  const float* enc = (const float*)d_in[1];
  const float* wq = (const float*)d_in[4];  const float* bq = (const float*)d_in[5];
  const float* wk = (const float*)d_in[6];  const float* bk = (const float*)d_in[7];
  const float* wv = (const float*)d_in[8];  const float* bv = (const float*)d_in[9];
  const float* wo = (const float*)d_in[10]; const float* bo = (const float*)d_in[11];
  const float* w1 = (const float*)d_in[12]; const float* b1 = (const float*)d_in[13];
  const float* w2 = (const float*)d_in[14]; const float* b2 = (const float*)d_in[15];
  const float* g1 = (const float*)d_in[16]; const float* be1 = (const float*)d_in[17];
  const float* g2 = (const float*)d_in[18]; const float* be2 = (const float*)d_in[19];
  float* out = (float*)d_out;

  const int M = 4096;  // B*L
  char* ws = (char*)d_ws;
  size_t off = 0;
  auto alloc = [&](size_t bytes) -> char* {
    char* p = ws + off;
    off += (bytes + 255) & ~(size_t)255;
    return p;
  };
  unsigned short* xb   = (unsigned short*)alloc((size_t)M * 1024 * 2);
  unsigned short* encb = (unsigned short*)alloc((size_t)M * 1024 * 2);
  unsigned short* wqb  = (unsigned short*)alloc((size_t)1024 * 1024 * 2);
  unsigned short* wkb  = (unsigned short*)alloc((size_t)1024 * 1024 * 2);
  unsigned short* wvb  = (unsigned short*)alloc((size_t)1024 * 1024 * 2);
  unsigned short* wob  = (unsigned short*)alloc((size_t)1024 * 1024 * 2);
  unsigned short* w1b  = (unsigned short*)alloc((size_t)4096 * 1024 * 2);
  unsigned short* w2b  = (unsigned short*)alloc((size_t)4096 * 1024 * 2);
  unsigned short* qb   = (unsigned short*)alloc((size_t)M * 1024 * 2);
  unsigned short* kp1  = (unsigned short*)alloc((size_t)M * 1024 * 2);  // contiguous group:
  unsigned short* vp1  = (unsigned short*)alloc((size_t)M * 1024 * 2);  //   aliased by hb
  unsigned short* kp2  = (unsigned short*)alloc((size_t)M * 1024 * 2);
  unsigned short* vp2  = (unsigned short*)alloc((size_t)M * 1024 * 2);
  unsigned short* ab   = (unsigned short*)alloc((size_t)M * 1024 * 2);
  float* s1 = (float*)alloc((size_t)2 * M * 1024 * 4);  // 2 halves for split-K
  float* y1 = (float*)alloc((size_t)M * 1024 * 4);
  unsigned short* hb = kp1;  // 32MB: kp1..vp2 all dead after attn2
  unsigned short* y1b = xb;  // xb dead after gemm_qkv_f
  unsigned short* y2b = qb;  // qb dead after attn2
  float* y2 = y1;            // y1 dead after O2 projection

  dim3 b256(256);
  cast8<<<dim3(256, 8), b256, 0, stream>>>(
      x, enc, wq, wk, wv, wo, w1, w2,
      xb, encb, wqb, wkb, wvb, wob, w1b, w2b,
      M * 1024 / 4, M * 1024 / 4, 262144, 262144, 262144, 262144,
      4096 * 1024 / 4, 4096 * 1024 / 4);

  // ---- all input-dependent projections in one launch (A-reuse fused) ----
  gemm_qkv_f<<<512, b256, 0, stream>>>(xb, encb, wqb, wkb, wvb, bq, bk, bv,
                                       qb, kp1, vp1, kp2, vp2);

  // ---- self attention ----
  attn_kernel<<<1024, b256, 0, stream>>>(qb, kp1, vp1, ab, 1);
  gemm_bt<0, 1, 1, 0, 64, 1><<<512, b256, 0, stream>>>(ab, wob, bo, x, s1, nullptr, M, 1024, 1024);
  ln_kernel<1, 1><<<4096, b256, 0, stream>>>(s1, g1, be1, y1, y1b);

  // ---- cross attention ----
  gemm_bt<0, 0, 0, 1, 64, 1><<<512, b256, 0, stream>>>(y1b, wqb, bq, nullptr, nullptr, qb, M, 1024, 1024);
  attn_kernel<<<1024, b256, 0, stream>>>(qb, kp2, vp2, ab, 0);
  gemm_bt<0, 1, 1, 0, 64, 1><<<512, b256, 0, stream>>>(ab, wob, bo, y1, s1, nullptr, M, 1024, 1024);
  ln_kernel<1, 1><<<4096, b256, 0, stream>>>(s1, g1, be1, y2, y2b);

  // ---- FFN ----
  gemm_bt<1, 0, 0, 1, 128, 1><<<1024, b256, 0, stream>>>(y2b, w1b, b1, nullptr, nullptr, hb, M, 4096, 1024);
  // FFN2: TM=128 tile at 2 blocks/CU via split-K=2 (grid 512; f32 partials).
  gemm_bt<0, 0, 1, 0, 128, 2><<<512, b256, 0, stream>>>(hb, w2b, b2, nullptr, s1, nullptr, M, 1024, 4096);
  ln2_kernel<<<4096, b256, 0, stream>>>(s1, s1 + (size_t)M * 1024, y2, g2, be2, out);

  (void)in_sizes; (void)n_in; (void)out_size; (void)ws_size;
}